// Round 2
// baseline (280.733 us; speedup 1.0000x reference)
//
#include <hip/hip_runtime.h>
#include <hip/hip_bf16.h>

// ---------------------------------------------------------------------------
// Qwen3 attention block on MI355X, bf16 MFMA pipeline:
//   cvt(fp32->bf16) -> gemm_bt(QKV, m97-style) -> norm+rope+cache
//   -> flash attn (GQA-shared staging, 8 waves) -> gemm_bt(O)
// Shapes: B=2 S=1024 HID=2048 H=32 KV=4 D=128; qkv row = 5120
// ---------------------------------------------------------------------------

typedef __attribute__((ext_vector_type(8))) __bf16 bf16x8;
typedef __attribute__((ext_vector_type(4))) __bf16 bf16x4;
typedef __attribute__((ext_vector_type(4))) float f32x4;

__device__ __forceinline__ void gload16(const void* g, void* l) {
    __builtin_amdgcn_global_load_lds((const __attribute__((address_space(1))) void*)g,
                                     (__attribute__((address_space(3))) void*)l, 16, 0, 0);
}

// ---------------- fp32 -> bf16 convert (grid-stride, float4) ----------------
__global__ __launch_bounds__(256) void cvt_f32_bf16(const float* __restrict__ src,
                                                    __bf16* __restrict__ dst, int n4) {
    int i = blockIdx.x * 256 + threadIdx.x;
    int stride = gridDim.x * 256;
    for (; i < n4; i += stride) {
        float4 v = reinterpret_cast<const float4*>(src)[i];
        bf16x4 o = {(__bf16)v.x, (__bf16)v.y, (__bf16)v.z, (__bf16)v.w};
        reinterpret_cast<bf16x4*>(dst)[i] = o;
    }
}

// ---------------- GEMM: C[m][n] = sum_k A[m][k]*B[n][k]  (B given row-major transposed)
// m97 structure: 128x128 tile, BK=64, 256 thr (2x2 waves), linear LDS + global_load_lds x16.
template <int OUT_BF16>
__global__ __launch_bounds__(256) void gemm_bt(const __bf16* __restrict__ A,
                                               const __bf16* __restrict__ B,
                                               void* __restrict__ C,
                                               const int M, const int N, const int K) {
    __shared__ __bf16 As[128 * 64];
    __shared__ __bf16 Bs[128 * 64];
    const int tid = threadIdx.x;
    const int lane = tid & 63;
    const int wave = tid >> 6;
    const int bn = blockIdx.x, bm = blockIdx.y;
    const int brow = bm * 128, bcol = bn * 128;
    const int wr = wave >> 1, wc = wave & 1;
    const int lrow = lane & 15, lkg = lane >> 4;
    const int srow_in = lane >> 3;        // 0..7 within chunk
    const int scol = (lane & 7) * 8;      // 0..56
    f32x4 acc[4][4] = {};

    for (int k0 = 0; k0 < K; k0 += 64) {
        __syncthreads();
#pragma unroll
        for (int r = 0; r < 4; ++r) {
            const int chunk = r * 4 + wave;          // 0..15, 8 rows each
            const int row = chunk * 8 + srow_in;
            gload16(&A[(size_t)(brow + row) * K + k0 + scol], &As[chunk * 512]);
            gload16(&B[(size_t)(bcol + row) * K + k0 + scol], &Bs[chunk * 512]);
        }
        __syncthreads();
#pragma unroll
        for (int kk = 0; kk < 2; ++kk) {
            bf16x8 a[4], bfr[4];
#pragma unroll
            for (int m = 0; m < 4; ++m)
                a[m] = *reinterpret_cast<const bf16x8*>(&As[(wr * 64 + m * 16 + lrow) * 64 + kk * 32 + lkg * 8]);
#pragma unroll
            for (int n = 0; n < 4; ++n)
                bfr[n] = *reinterpret_cast<const bf16x8*>(&Bs[(wc * 64 + n * 16 + lrow) * 64 + kk * 32 + lkg * 8]);
#pragma unroll
            for (int m = 0; m < 4; ++m)
#pragma unroll
                for (int n = 0; n < 4; ++n)
                    acc[m][n] = __builtin_amdgcn_mfma_f32_16x16x32_bf16(a[m], bfr[n], acc[m][n], 0, 0, 0);
        }
    }
#pragma unroll
    for (int m = 0; m < 4; ++m)
#pragma unroll
        for (int n = 0; n < 4; ++n)
#pragma unroll
            for (int j = 0; j < 4; ++j) {
                const size_t r = brow + wr * 64 + m * 16 + lkg * 4 + j;
                const size_t c = bcol + wc * 64 + n * 16 + lrow;
                if (OUT_BF16)
                    ((__bf16*)C)[r * N + c] = (__bf16)acc[m][n][j];
                else
                    ((float*)C)[r * N + c] = acc[m][n][j];
            }
}

// ---------------- per-token RMSNorm + RoPE + paged cache scatter ----------------
__global__ __launch_bounds__(256) void norm_rope_cache(
    __bf16* __restrict__ qkv, const float* __restrict__ cosT, const float* __restrict__ sinT,
    const float* __restrict__ qw, const float* __restrict__ kw,
    const int* __restrict__ ptab, float* __restrict__ cacheK, float* __restrict__ cacheV) {
    const int t = blockIdx.x;
    const int b = t >> 10, s = t & 1023;
    const int wave = threadIdx.x >> 6, lane = threadIdx.x & 63;
    __bf16* row = qkv + (size_t)t * 5120;
    const float c = cosT[s * 128 + lane];   // cos[d+64] == cos[d]
    const float sn = sinT[s * 128 + lane];
    const int page = ptab[b * 32 + (s >> 5)];
    const int so = s & 31;
    const float wq0 = qw[lane], wq1 = qw[lane + 64];
#pragma unroll
    for (int i = 0; i < 8; ++i) {
        const int h = wave * 8 + i;
        float x0 = (float)row[h * 128 + lane];
        float x1 = (float)row[h * 128 + 64 + lane];
        float ss = x0 * x0 + x1 * x1;
        for (int off = 32; off; off >>= 1) ss += __shfl_xor(ss, off);
        const float rs = rsqrtf(ss * (1.0f / 128.0f) + 1e-6f);
        const float y0 = x0 * rs * wq0, y1 = x1 * rs * wq1;
        row[h * 128 + lane]      = (__bf16)(y0 * c - y1 * sn);
        row[h * 128 + 64 + lane] = (__bf16)(y1 * c + y0 * sn);
    }
    {
        const int h = wave;
        float x0 = (float)row[4096 + h * 128 + lane];
        float x1 = (float)row[4096 + h * 128 + 64 + lane];
        float ss = x0 * x0 + x1 * x1;
        for (int off = 32; off; off >>= 1) ss += __shfl_xor(ss, off);
        const float rs = rsqrtf(ss * (1.0f / 128.0f) + 1e-6f);
        const float y0 = x0 * rs * kw[lane], y1 = x1 * rs * kw[lane + 64];
        const float o0 = y0 * c - y1 * sn, o1 = y1 * c + y0 * sn;
        row[4096 + h * 128 + lane]      = (__bf16)o0;
        row[4096 + h * 128 + 64 + lane] = (__bf16)o1;
        float* ck = cacheK + (((size_t)page * 4 + h) * 32 + so) * 128;
        ck[lane] = o0; ck[lane + 64] = o1;
        const float v0 = (float)row[4608 + h * 128 + lane];
        const float v1 = (float)row[4608 + h * 128 + 64 + lane];
        float* cv = cacheV + (((size_t)page * 4 + h) * 32 + so) * 128;
        cv[lane] = v0; cv[lane + 64] = v1;
    }
}

// ---------------- flash attention, causal GQA, shared K/V staging ----------------
// grid (qb16=64 reversed, kvg=4, b=2), 512 thr = 8 waves; wave w = head kvg*8+w,
// all waves share the same 16 q-rows. KVBLK=64, staged once per block per tile.
// K: global_load_lds linear dest + source-swizzle, XOR-swizzled ds_read (T2/m201).
__global__ __launch_bounds__(512) void attn_fwd(const __bf16* __restrict__ qkv,
                                                __bf16* __restrict__ out) {
    constexpr int LVT = 72, LPT = 72;
    __shared__ __bf16 Ks[64 * 128];      // linear, swizzled content (16 KB)
    __shared__ __bf16 Vt[128 * LVT];     // transposed V [d][kv] (18 KB)
    __shared__ __bf16 Ps[8 * 16 * LPT];  // per-wave P tile [q][kv] (18 KB)
    const int qb = 63 - blockIdx.x;      // long blocks first
    const int kvg = blockIdx.y, b = blockIdx.z;
    const int tid = threadIdx.x, wave = tid >> 6, lane = tid & 63;
    const int lrow = lane & 15, lkg = lane >> 4;
    const int h = kvg * 8 + wave;
    const size_t base = (size_t)b * 1024 * 5120;
    const int kofs = 4096 + kvg * 128, vofs = 4608 + kvg * 128;
    const int qrow0 = qb * 16;

    // Q fragments (B-operand): aq[kc][i] = Q[qrow0+lrow][kc*32+lkg*8+i]
    bf16x8 aq[4];
#pragma unroll
    for (int kc = 0; kc < 4; ++kc)
        aq[kc] = *reinterpret_cast<const bf16x8*>(
            &qkv[base + (size_t)(qrow0 + lrow) * 5120 + h * 128 + kc * 32 + lkg * 8]);

    f32x4 acc[8] = {};   // O[q=lkg*4+j][d=f*16+lrow]
    float m_i = -1e30f, l_i = 0.f;
    const int nt = qb / 4 + 1;
    __bf16* Pw = &Ps[wave * 16 * LPT];
    const int swz = lrow & 7;

    for (int t = 0; t < nt; ++t) {
        const int kv0 = t * 64;
        __syncthreads();   // prior-tile LDS reads done
        // K tile: 64x128 bf16 via global_load_lds; source pre-swizzled so that
        // LDS[r][slot s] = G[r][s ^ (r&7)]  (16B slots)
#pragma unroll
        for (int c = 0; c < 2; ++c) {
            const int chunk = c * 8 + wave;           // 1 KB per wave-call
            const int row = chunk * 4 + (lane >> 4);  // 4 rows per chunk
            const int gslot = (lane & 15) ^ (row & 7);
            gload16(&qkv[base + (size_t)(kv0 + row) * 5120 + kofs + gslot * 8],
                    &Ks[chunk * 512]);
        }
        // V tile transposed: thread -> kv=lane, d-chunk = wave(+8r); writes are
        // lane-contiguous along kv (2 lanes/bank, free)
#pragma unroll
        for (int r = 0; r < 2; ++r) {
            const int d0 = (wave + r * 8) * 8;
            uint4 vv = *reinterpret_cast<const uint4*>(
                &qkv[base + (size_t)(kv0 + lane) * 5120 + vofs + d0]);
            const __bf16* pv = reinterpret_cast<const __bf16*>(&vv);
#pragma unroll
            for (int j = 0; j < 8; ++j) Vt[(d0 + j) * LVT + lane] = pv[j];
        }
        __syncthreads();

        // QK^T: St[kv 0..63][q 0..15], swizzled K reads
        f32x4 st[4] = {};
#pragma unroll
        for (int kc = 0; kc < 4; ++kc)
#pragma unroll
            for (int f = 0; f < 4; ++f) {
                bf16x8 ak = *reinterpret_cast<const bf16x8*>(
                    &Ks[(f * 16 + lrow) * 128 + ((kc * 4 + lkg) ^ swz) * 8]);
                st[f] = __builtin_amdgcn_mfma_f32_16x16x32_bf16(ak, aq[kc], st[f], 0, 0, 0);
            }

        // scale + causal mask + online softmax (lane's q col = qrow0+lrow)
        const int qpos = qrow0 + lrow;
        float sv[16];
        float pmax = -1e30f;
#pragma unroll
        for (int f = 0; f < 4; ++f)
#pragma unroll
            for (int j = 0; j < 4; ++j) {
                const int kvpos = kv0 + f * 16 + lkg * 4 + j;
                float x = st[f][j] * 0.08838834764831845f;
                if (kvpos > qpos) x = -1e30f;
                sv[f * 4 + j] = x;
                pmax = fmaxf(pmax, x);
            }
        pmax = fmaxf(pmax, __shfl_xor(pmax, 16));
        pmax = fmaxf(pmax, __shfl_xor(pmax, 32));
        const float m_new = fmaxf(m_i, pmax);
        const float sf = __expf(m_i - m_new);
        float ladd = 0.f;
#pragma unroll
        for (int f = 0; f < 4; ++f) {
            bf16x4 pb;
#pragma unroll
            for (int j = 0; j < 4; ++j) {
                const float p = __expf(sv[f * 4 + j] - m_new);
                ladd += p;
                pb[j] = (__bf16)p;
            }
            *reinterpret_cast<bf16x4*>(&Pw[lrow * LPT + f * 16 + lkg * 4]) = pb;
        }
        ladd += __shfl_xor(ladd, 16);
        ladd += __shfl_xor(ladd, 32);
        l_i = l_i * sf + ladd;
        m_i = m_new;
        float sfj[4];
#pragma unroll
        for (int j = 0; j < 4; ++j) sfj[j] = __shfl(sf, lkg * 4 + j);
#pragma unroll
        for (int f = 0; f < 8; ++f)
#pragma unroll
            for (int j = 0; j < 4; ++j) acc[f][j] *= sfj[j];

        // PV: A = P[q][kv] (wave-local LDS), B = V[kv][d] via transposed Vt
#pragma unroll
        for (int kk = 0; kk < 2; ++kk) {
            bf16x8 ap = *reinterpret_cast<const bf16x8*>(&Pw[lrow * LPT + kk * 32 + lkg * 8]);
#pragma unroll
            for (int f = 0; f < 8; ++f) {
                bf16x8 bv = *reinterpret_cast<const bf16x8*>(
                    &Vt[(f * 16 + lrow) * LVT + kk * 32 + lkg * 8]);
                acc[f] = __builtin_amdgcn_mfma_f32_16x16x32_bf16(ap, bv, acc[f], 0, 0, 0);
            }
        }
    }
    // epilogue
    float linv[4];
#pragma unroll
    for (int j = 0; j < 4; ++j) linv[j] = 1.0f / __shfl(l_i, lkg * 4 + j);
#pragma unroll
    for (int f = 0; f < 8; ++f)
#pragma unroll
        for (int j = 0; j < 4; ++j) {
            const size_t r = (size_t)b * 1024 + qrow0 + lkg * 4 + j;
            out[r * 4096 + h * 128 + f * 16 + lrow] = (__bf16)(acc[f][j] * linv[j]);
        }
}

// ---------------------------------------------------------------------------
extern "C" void kernel_launch(void* const* d_in, const int* in_sizes, int n_in,
                              void* d_out, int out_size, void* d_ws, size_t ws_size,
                              hipStream_t stream) {
    const float* hidden = (const float*)d_in[0];
    const float* wq = (const float*)d_in[1];
    const float* wk = (const float*)d_in[2];
    const float* wv = (const float*)d_in[3];
    const float* wo = (const float*)d_in[4];
    const float* qnw = (const float*)d_in[5];
    const float* knw = (const float*)d_in[6];
    const float* cosT = (const float*)d_in[7];
    const float* sinT = (const float*)d_in[8];
    const int* ptab = (const int*)d_in[9];

    float* outp = (float*)d_out;                 // (2,1024,2048)
    float* cacheK = outp + 4194304;              // (128,4,32,128)
    float* cacheV = cacheK + 2097152;

    char* ws = (char*)d_ws;
    __bf16* hbf    = (__bf16*)ws;                       // 2048x2048
    __bf16* w1bf   = (__bf16*)(ws + 8388608);           // 5120x2048 (wq|wk|wv)
    __bf16* wobf   = (__bf16*)(ws + 29360128);          // 2048x4096
    __bf16* qkvbf  = (__bf16*)(ws + 46137344);          // 2048x5120
    __bf16* attnbf = (__bf16*)ws;                       // 2048x4096 (overlay: hbf/w1bf dead)

    cvt_f32_bf16<<<2048, 256, 0, stream>>>(hidden, hbf, 2048 * 2048 / 4);
    cvt_f32_bf16<<<2048, 256, 0, stream>>>(wq, w1bf, 4096 * 2048 / 4);
    cvt_f32_bf16<<<512, 256, 0, stream>>>(wk, w1bf + (size_t)4096 * 2048, 512 * 2048 / 4);
    cvt_f32_bf16<<<512, 256, 0, stream>>>(wv, w1bf + (size_t)4608 * 2048, 512 * 2048 / 4);
    cvt_f32_bf16<<<2048, 256, 0, stream>>>(wo, wobf, 2048 * 4096 / 4);

    // QKV projection: (2048x2048) @ (5120x2048)^T -> qkvbf bf16
    gemm_bt<1><<<dim3(40, 16), 256, 0, stream>>>(hbf, w1bf, qkvbf, 2048, 5120, 2048);

    hipMemsetAsync(cacheK, 0, (size_t)4194304 * 4, stream);
    norm_rope_cache<<<2048, 256, 0, stream>>>(qkvbf, cosT, sinT, qnw, knw, ptab, cacheK, cacheV);

    attn_fwd<<<dim3(64, 4, 2), 512, 0, stream>>>(qkvbf, attnbf);

    // out projection: (2048x4096) @ (2048x4096)^T -> fp32 d_out
    gemm_bt<0><<<dim3(16, 16), 256, 0, stream>>>(attnbf, wobf, outp, 2048, 2048, 4096);
}

// Round 3
// 238.669 us; speedup vs baseline: 1.1762x; 1.1762x over previous
//
#include <hip/hip_runtime.h>
#include <hip/hip_bf16.h>

// ---------------------------------------------------------------------------
// Qwen3 attention block on MI355X, bf16 MFMA pipeline:
//   cvt(fp32->bf16) -> gemm_bt 2-phase dbuf (QKV) -> norm+rope+cache
//   -> flash attn (GQA-shared staging) -> gemm_bt splitK2 (O) -> reduce
// Shapes: B=2 S=1024 HID=2048 H=32 KV=4 D=128; qkv row = 5120
// ---------------------------------------------------------------------------

typedef __attribute__((ext_vector_type(8))) __bf16 bf16x8;
typedef __attribute__((ext_vector_type(4))) __bf16 bf16x4;
typedef __attribute__((ext_vector_type(4))) float f32x4;

__device__ __forceinline__ void gload16(const void* g, void* l) {
    __builtin_amdgcn_global_load_lds((const __attribute__((address_space(1))) void*)g,
                                     (__attribute__((address_space(3))) void*)l, 16, 0, 0);
}

// ---------------- fp32 -> bf16 convert (grid-stride, float4) ----------------
__global__ __launch_bounds__(256) void cvt_f32_bf16(const float* __restrict__ src,
                                                    __bf16* __restrict__ dst, int n4) {
    int i = blockIdx.x * 256 + threadIdx.x;
    int stride = gridDim.x * 256;
    for (; i < n4; i += stride) {
        float4 v = reinterpret_cast<const float4*>(src)[i];
        bf16x4 o = {(__bf16)v.x, (__bf16)v.y, (__bf16)v.z, (__bf16)v.w};
        reinterpret_cast<bf16x4*>(dst)[i] = o;
    }
}

// ---------------- o[i] += p[i] (split-K reduce) ----------------
__global__ __launch_bounds__(256) void reduce_add(float* __restrict__ o,
                                                  const float* __restrict__ p, int n4) {
    int i = blockIdx.x * 256 + threadIdx.x;
    int stride = gridDim.x * 256;
    for (; i < n4; i += stride) {
        float4 a = reinterpret_cast<float4*>(o)[i];
        float4 b = reinterpret_cast<const float4*>(p)[i];
        a.x += b.x; a.y += b.y; a.z += b.z; a.w += b.w;
        reinterpret_cast<float4*>(o)[i] = a;
    }
}

// ---------------- GEMM: C[m][n] = sum_k A[m][k]*B[n][k]  (B row-major transposed)
// 128x128 tile, BK=64, 256 thr (2x2 waves), global_load_lds staging,
// 2-phase double-buffer: stage tile t+1 while MFMA-ing tile t; 1 barrier/K-tile.
// blockIdx.z selects a K-split half: kbeg = z*klen; z==0 -> C0, z==1 -> C1.
template <int OUT_BF16>
__global__ __launch_bounds__(256) void gemm_bt(const __bf16* __restrict__ A,
                                               const __bf16* __restrict__ B,
                                               void* __restrict__ C0,
                                               void* __restrict__ C1,
                                               const int M, const int N, const int K,
                                               const int klen) {
    __shared__ __bf16 As0[128 * 64];
    __shared__ __bf16 Bs0[128 * 64];
    __shared__ __bf16 As1[128 * 64];
    __shared__ __bf16 Bs1[128 * 64];
    const int tid = threadIdx.x;
    const int lane = tid & 63;
    const int wave = tid >> 6;
    const int bn = blockIdx.x, bm = blockIdx.y;
    const int kbeg = blockIdx.z * klen;
    const int brow = bm * 128, bcol = bn * 128;
    const int wr = wave >> 1, wc = wave & 1;
    const int lrow = lane & 15, lkg = lane >> 4;
    const int srow_in = lane >> 3;        // 0..7 within chunk
    const int scol = (lane & 7) * 8;      // 0..56
    f32x4 acc[4][4] = {};

    auto stage = [&](int k0, __bf16* as, __bf16* bs) {
#pragma unroll
        for (int r = 0; r < 4; ++r) {
            const int chunk = r * 4 + wave;          // 0..15, 8 rows each
            const int row = chunk * 8 + srow_in;
            gload16(&A[(size_t)(brow + row) * K + k0 + scol], as + chunk * 512);
            gload16(&B[(size_t)(bcol + row) * K + k0 + scol], bs + chunk * 512);
        }
    };
    auto compute = [&](const __bf16* as, const __bf16* bs) {
#pragma unroll
        for (int kk = 0; kk < 2; ++kk) {
            bf16x8 a[4], bfr[4];
#pragma unroll
            for (int m = 0; m < 4; ++m)
                a[m] = *reinterpret_cast<const bf16x8*>(&as[(wr * 64 + m * 16 + lrow) * 64 + kk * 32 + lkg * 8]);
#pragma unroll
            for (int n = 0; n < 4; ++n)
                bfr[n] = *reinterpret_cast<const bf16x8*>(&bs[(wc * 64 + n * 16 + lrow) * 64 + kk * 32 + lkg * 8]);
#pragma unroll
            for (int m = 0; m < 4; ++m)
#pragma unroll
                for (int n = 0; n < 4; ++n)
                    acc[m][n] = __builtin_amdgcn_mfma_f32_16x16x32_bf16(a[m], bfr[n], acc[m][n], 0, 0, 0);
        }
    };

    const int nt = klen / 64;   // even (K multiples of 128)
    stage(kbeg, As0, Bs0);
    asm volatile("s_waitcnt vmcnt(0)" ::: "memory");
    __syncthreads();
    int t = 0;
    for (; t + 2 < nt; t += 2) {
        stage(kbeg + (t + 1) * 64, As1, Bs1);
        compute(As0, Bs0);
        asm volatile("s_waitcnt vmcnt(0)" ::: "memory");
        __syncthreads();
        stage(kbeg + (t + 2) * 64, As0, Bs0);
        compute(As1, Bs1);
        asm volatile("s_waitcnt vmcnt(0)" ::: "memory");
        __syncthreads();
    }
    stage(kbeg + (t + 1) * 64, As1, Bs1);
    compute(As0, Bs0);
    asm volatile("s_waitcnt vmcnt(0)" ::: "memory");
    __syncthreads();
    compute(As1, Bs1);

    void* C = blockIdx.z == 0 ? C0 : C1;
#pragma unroll
    for (int m = 0; m < 4; ++m)
#pragma unroll
        for (int n = 0; n < 4; ++n)
#pragma unroll
            for (int j = 0; j < 4; ++j) {
                const size_t r = brow + wr * 64 + m * 16 + lkg * 4 + j;
                const size_t c = bcol + wc * 64 + n * 16 + lrow;
                if (OUT_BF16)
                    ((__bf16*)C)[r * N + c] = (__bf16)acc[m][n][j];
                else
                    ((float*)C)[r * N + c] = acc[m][n][j];
            }
}

// ---------------- per-token RMSNorm + RoPE + paged cache scatter ----------------
__global__ __launch_bounds__(256) void norm_rope_cache(
    __bf16* __restrict__ qkv, const float* __restrict__ cosT, const float* __restrict__ sinT,
    const float* __restrict__ qw, const float* __restrict__ kw,
    const int* __restrict__ ptab, float* __restrict__ cacheK, float* __restrict__ cacheV) {
    const int t = blockIdx.x;
    const int b = t >> 10, s = t & 1023;
    const int wave = threadIdx.x >> 6, lane = threadIdx.x & 63;
    __bf16* row = qkv + (size_t)t * 5120;
    const float c = cosT[s * 128 + lane];   // cos[d+64] == cos[d]
    const float sn = sinT[s * 128 + lane];
    const int page = ptab[b * 32 + (s >> 5)];
    const int so = s & 31;
    const float wq0 = qw[lane], wq1 = qw[lane + 64];
#pragma unroll
    for (int i = 0; i < 8; ++i) {
        const int h = wave * 8 + i;
        float x0 = (float)row[h * 128 + lane];
        float x1 = (float)row[h * 128 + 64 + lane];
        float ss = x0 * x0 + x1 * x1;
        for (int off = 32; off; off >>= 1) ss += __shfl_xor(ss, off);
        const float rs = rsqrtf(ss * (1.0f / 128.0f) + 1e-6f);
        const float y0 = x0 * rs * wq0, y1 = x1 * rs * wq1;
        row[h * 128 + lane]      = (__bf16)(y0 * c - y1 * sn);
        row[h * 128 + 64 + lane] = (__bf16)(y1 * c + y0 * sn);
    }
    {
        const int h = wave;
        float x0 = (float)row[4096 + h * 128 + lane];
        float x1 = (float)row[4096 + h * 128 + 64 + lane];
        float ss = x0 * x0 + x1 * x1;
        for (int off = 32; off; off >>= 1) ss += __shfl_xor(ss, off);
        const float rs = rsqrtf(ss * (1.0f / 128.0f) + 1e-6f);
        const float y0 = x0 * rs * kw[lane], y1 = x1 * rs * kw[lane + 64];
        const float o0 = y0 * c - y1 * sn, o1 = y1 * c + y0 * sn;
        row[4096 + h * 128 + lane]      = (__bf16)o0;
        row[4096 + h * 128 + 64 + lane] = (__bf16)o1;
        float* ck = cacheK + (((size_t)page * 4 + h) * 32 + so) * 128;
        ck[lane] = o0; ck[lane + 64] = o1;
        const float v0 = (float)row[4608 + h * 128 + lane];
        const float v1 = (float)row[4608 + h * 128 + 64 + lane];
        float* cv = cacheV + (((size_t)page * 4 + h) * 32 + so) * 128;
        cv[lane] = v0; cv[lane + 64] = v1;
    }
}

// ---------------- flash attention, causal GQA, shared K/V staging ----------------
// grid (qb16=64 reversed, kvg=4, b=2), 512 thr = 8 waves; wave w = head kvg*8+w,
// all waves share the same 16 q-rows. KVBLK=64, staged once per block per tile.
__global__ __launch_bounds__(512) void attn_fwd(const __bf16* __restrict__ qkv,
                                                __bf16* __restrict__ out) {
    constexpr int LVT = 72, LPT = 72;
    __shared__ __bf16 Ks[64 * 128];      // linear, swizzled content (16 KB)
    __shared__ __bf16 Vt[128 * LVT];     // transposed V [d][kv] (18 KB)
    __shared__ __bf16 Ps[8 * 16 * LPT];  // per-wave P tile [q][kv] (18 KB)
    const int qb = 63 - blockIdx.x;      // long blocks first
    const int kvg = blockIdx.y, b = blockIdx.z;
    const int tid = threadIdx.x, wave = tid >> 6, lane = tid & 63;
    const int lrow = lane & 15, lkg = lane >> 4;
    const int h = kvg * 8 + wave;
    const size_t base = (size_t)b * 1024 * 5120;
    const int kofs = 4096 + kvg * 128, vofs = 4608 + kvg * 128;
    const int qrow0 = qb * 16;

    bf16x8 aq[4];
#pragma unroll
    for (int kc = 0; kc < 4; ++kc)
        aq[kc] = *reinterpret_cast<const bf16x8*>(
            &qkv[base + (size_t)(qrow0 + lrow) * 5120 + h * 128 + kc * 32 + lkg * 8]);

    f32x4 acc[8] = {};   // O[q=lkg*4+j][d=f*16+lrow]
    float m_i = -1e30f, l_i = 0.f;
    const int nt = qb / 4 + 1;
    __bf16* Pw = &Ps[wave * 16 * LPT];
    const int swz = lrow & 7;

    for (int t = 0; t < nt; ++t) {
        const int kv0 = t * 64;
        __syncthreads();
        // K tile: LDS[r][slot s] = G[r][s ^ (r&7)]  (16B slots)
#pragma unroll
        for (int c = 0; c < 2; ++c) {
            const int chunk = c * 8 + wave;
            const int row = chunk * 4 + (lane >> 4);
            const int gslot = (lane & 15) ^ (row & 7);
            gload16(&qkv[base + (size_t)(kv0 + row) * 5120 + kofs + gslot * 8],
                    &Ks[chunk * 512]);
        }
#pragma unroll
        for (int r = 0; r < 2; ++r) {
            const int d0 = (wave + r * 8) * 8;
            uint4 vv = *reinterpret_cast<const uint4*>(
                &qkv[base + (size_t)(kv0 + lane) * 5120 + vofs + d0]);
            const __bf16* pv = reinterpret_cast<const __bf16*>(&vv);
#pragma unroll
            for (int j = 0; j < 8; ++j) Vt[(d0 + j) * LVT + lane] = pv[j];
        }
        __syncthreads();

        f32x4 st[4] = {};
#pragma unroll
        for (int kc = 0; kc < 4; ++kc)
#pragma unroll
            for (int f = 0; f < 4; ++f) {
                bf16x8 ak = *reinterpret_cast<const bf16x8*>(
                    &Ks[(f * 16 + lrow) * 128 + ((kc * 4 + lkg) ^ swz) * 8]);
                st[f] = __builtin_amdgcn_mfma_f32_16x16x32_bf16(ak, aq[kc], st[f], 0, 0, 0);
            }

        const int qpos = qrow0 + lrow;
        float sv[16];
        float pmax = -1e30f;
#pragma unroll
        for (int f = 0; f < 4; ++f)
#pragma unroll
            for (int j = 0; j < 4; ++j) {
                const int kvpos = kv0 + f * 16 + lkg * 4 + j;
                float x = st[f][j] * 0.08838834764831845f;
                if (kvpos > qpos) x = -1e30f;
                sv[f * 4 + j] = x;
                pmax = fmaxf(pmax, x);
            }
        pmax = fmaxf(pmax, __shfl_xor(pmax, 16));
        pmax = fmaxf(pmax, __shfl_xor(pmax, 32));
        const float m_new = fmaxf(m_i, pmax);
        const float sf = __expf(m_i - m_new);
        float ladd = 0.f;
#pragma unroll
        for (int f = 0; f < 4; ++f) {
            bf16x4 pb;
#pragma unroll
            for (int j = 0; j < 4; ++j) {
                const float p = __expf(sv[f * 4 + j] - m_new);
                ladd += p;
                pb[j] = (__bf16)p;
            }
            *reinterpret_cast<bf16x4*>(&Pw[lrow * LPT + f * 16 + lkg * 4]) = pb;
        }
        ladd += __shfl_xor(ladd, 16);
        ladd += __shfl_xor(ladd, 32);
        l_i = l_i * sf + ladd;
        m_i = m_new;
        float sfj[4];
#pragma unroll
        for (int j = 0; j < 4; ++j) sfj[j] = __shfl(sf, lkg * 4 + j);
#pragma unroll
        for (int f = 0; f < 8; ++f)
#pragma unroll
            for (int j = 0; j < 4; ++j) acc[f][j] *= sfj[j];

#pragma unroll
        for (int kk = 0; kk < 2; ++kk) {
            bf16x8 ap = *reinterpret_cast<const bf16x8*>(&Pw[lrow * LPT + kk * 32 + lkg * 8]);
#pragma unroll
            for (int f = 0; f < 8; ++f) {
                bf16x8 bv = *reinterpret_cast<const bf16x8*>(
                    &Vt[(f * 16 + lrow) * LVT + kk * 32 + lkg * 8]);
                acc[f] = __builtin_amdgcn_mfma_f32_16x16x32_bf16(ap, bv, acc[f], 0, 0, 0);
            }
        }
    }
    float linv[4];
#pragma unroll
    for (int j = 0; j < 4; ++j) linv[j] = 1.0f / __shfl(l_i, lkg * 4 + j);
#pragma unroll
    for (int f = 0; f < 8; ++f)
#pragma unroll
        for (int j = 0; j < 4; ++j) {
            const size_t r = (size_t)b * 1024 + qrow0 + lkg * 4 + j;
            out[r * 4096 + h * 128 + f * 16 + lrow] = (__bf16)(acc[f][j] * linv[j]);
        }
}

// ---------------------------------------------------------------------------
extern "C" void kernel_launch(void* const* d_in, const int* in_sizes, int n_in,
                              void* d_out, int out_size, void* d_ws, size_t ws_size,
                              hipStream_t stream) {
    const float* hidden = (const float*)d_in[0];
    const float* wq = (const float*)d_in[1];
    const float* wk = (const float*)d_in[2];
    const float* wv = (const float*)d_in[3];
    const float* wo = (const float*)d_in[4];
    const float* qnw = (const float*)d_in[5];
    const float* knw = (const float*)d_in[6];
    const float* cosT = (const float*)d_in[7];
    const float* sinT = (const float*)d_in[8];
    const int* ptab = (const int*)d_in[9];

    float* outp = (float*)d_out;                 // (2,1024,2048)
    float* cacheK = outp + 4194304;              // (128,4,32,128)
    float* cacheV = cacheK + 2097152;

    char* ws = (char*)d_ws;
    __bf16* hbf    = (__bf16*)ws;                       // 2048x2048
    __bf16* w1bf   = (__bf16*)(ws + 8388608);           // 5120x2048 (wq|wk|wv)
    __bf16* wobf   = (__bf16*)(ws + 29360128);          // 2048x4096
    __bf16* qkvbf  = (__bf16*)(ws + 46137344);          // 2048x5120
    __bf16* attnbf = (__bf16*)ws;                       // 2048x4096 (overlay: hbf/w1bf dead)
    float*  opart  = (float*)(ws + 46137344);           // 2048x2048 f32 (overlay: qkvbf dead)

    cvt_f32_bf16<<<2048, 256, 0, stream>>>(hidden, hbf, 2048 * 2048 / 4);
    cvt_f32_bf16<<<2048, 256, 0, stream>>>(wq, w1bf, 4096 * 2048 / 4);
    cvt_f32_bf16<<<512, 256, 0, stream>>>(wk, w1bf + (size_t)4096 * 2048, 512 * 2048 / 4);
    cvt_f32_bf16<<<512, 256, 0, stream>>>(wv, w1bf + (size_t)4608 * 2048, 512 * 2048 / 4);
    cvt_f32_bf16<<<2048, 256, 0, stream>>>(wo, wobf, 2048 * 4096 / 4);

    // QKV projection: (2048x2048) @ (5120x2048)^T -> qkvbf bf16
    gemm_bt<1><<<dim3(40, 16, 1), 256, 0, stream>>>(hbf, w1bf, qkvbf, nullptr,
                                                    2048, 5120, 2048, 2048);

    hipMemsetAsync(cacheK, 0, (size_t)4194304 * 4, stream);
    norm_rope_cache<<<2048, 256, 0, stream>>>(qkvbf, cosT, sinT, qnw, knw, ptab, cacheK, cacheV);

    attn_fwd<<<dim3(64, 4, 2), 512, 0, stream>>>(qkvbf, attnbf);

    // out projection, split-K2: (2048x4096) @ (2048x4096)^T -> f32
    gemm_bt<0><<<dim3(16, 16, 2), 256, 0, stream>>>(attnbf, wobf, outp, opart,
                                                    2048, 2048, 4096, 2048);
    reduce_add<<<2048, 256, 0, stream>>>(outp, opart, 4194304 / 4);
}

// Round 4
// 217.158 us; speedup vs baseline: 1.2928x; 1.0991x over previous
//
#include <hip/hip_runtime.h>
#include <hip/hip_bf16.h>

// ---------------------------------------------------------------------------
// Qwen3 attention block on MI355X, bf16 MFMA pipeline:
//   cvt5 -> gemm256 8-phase (QKV) -> norm+rope+cache -> flash attn
//   -> gemm_bt 2-phase splitK2 (O) -> reduce
// Shapes: B=2 S=1024 HID=2048 H=32 KV=4 D=128; qkv row = 5120
// ---------------------------------------------------------------------------

typedef __attribute__((ext_vector_type(8))) __bf16 bf16x8;
typedef __attribute__((ext_vector_type(4))) __bf16 bf16x4;
typedef __attribute__((ext_vector_type(4))) float f32x4;

__device__ __forceinline__ void gload16(const void* g, void* l) {
    __builtin_amdgcn_global_load_lds((const __attribute__((address_space(1))) void*)g,
                                     (__attribute__((address_space(3))) void*)l, 16, 0, 0);
}

// ---------------- fused fp32 -> bf16 convert, 5 segments, 1 f4/thread -------
__global__ __launch_bounds__(256) void cvt5(const float* __restrict__ s0, const float* __restrict__ s1,
                                            const float* __restrict__ s2, const float* __restrict__ s3,
                                            const float* __restrict__ s4,
                                            __bf16* __restrict__ d0, __bf16* __restrict__ d1,
                                            __bf16* __restrict__ d2, __bf16* __restrict__ d3,
                                            __bf16* __restrict__ d4) {
    const int b = blockIdx.x;
    const float* src; __bf16* dst; int off;
    if (b < 4096)       { src = s0; dst = d0; off = b; }
    else if (b < 12288) { src = s1; dst = d1; off = b - 4096; }
    else if (b < 13312) { src = s2; dst = d2; off = b - 12288; }
    else if (b < 14336) { src = s3; dst = d3; off = b - 13312; }
    else                { src = s4; dst = d4; off = b - 14336; }
    const int i = off * 256 + threadIdx.x;
    float4 v = reinterpret_cast<const float4*>(src)[i];
    bf16x4 o = {(__bf16)v.x, (__bf16)v.y, (__bf16)v.z, (__bf16)v.w};
    reinterpret_cast<bf16x4*>(dst)[i] = o;
}

// ---------------- o[i] += p[i] (split-K reduce) ----------------
__global__ __launch_bounds__(256) void reduce_add(float* __restrict__ o,
                                                  const float* __restrict__ p, int n4) {
    int i = blockIdx.x * 256 + threadIdx.x;
    int stride = gridDim.x * 256;
    for (; i < n4; i += stride) {
        float4 a = reinterpret_cast<float4*>(o)[i];
        float4 b = reinterpret_cast<const float4*>(p)[i];
        a.x += b.x; a.y += b.y; a.z += b.z; a.w += b.w;
        reinterpret_cast<float4*>(o)[i] = a;
    }
}

// ---------------- 256x256 8-phase GEMM: C[m][n] = sum_k A[m][k]*B[n][k], bf16 out
// 512 thr = 8 waves (2m x 4n), BK=64, 2 K-tiles/iter, 8 phases/iter.
// LDS 128KB: A,B each 2 x 256x64. Read-swizzle slot^=(row&7), source pre-swizzled.
// Stage schedule: half-tile s at global phase s-5; vmcnt(2) publishes at p3/p7.
__global__ __launch_bounds__(512, 2) void gemm256(const __bf16* __restrict__ A,
                                                  const __bf16* __restrict__ B,
                                                  __bf16* __restrict__ C,
                                                  const int M, const int N, const int K) {
    __shared__ __bf16 Asm[2 * 256 * 64];
    __shared__ __bf16 Bsm[2 * 256 * 64];
    const int tid = threadIdx.x, lane = tid & 63, wave = tid >> 6;
    const int wm = wave >> 2, wn = wave & 3;
    const int lrow = lane & 15, lkg = lane >> 4;
    const int nbn = N >> 8;
    const int swz = ((int)blockIdx.x & 7) * ((int)gridDim.x >> 3) + ((int)blockIdx.x >> 3);
    const int bm = swz / nbn, bn = swz % nbn;
    const int brow = bm * 256, bcol = bn * 256;
    const int row0 = tid >> 3;                       // 0..63
    const int scol_sw = ((tid & 7) ^ (row0 & 7)) * 8;  // pre-swizzled source col
    const __bf16* gA = A + (size_t)(brow + row0) * K + scol_sw;
    const __bf16* gB = B + (size_t)(bcol + row0) * K + scol_sw;
    const int aslot0 = (lkg ^ (lrow & 7)) * 8;        // kk=0 read slot (elems)
    const int aslot1 = ((4 + lkg) ^ (lrow & 7)) * 8;  // kk=1
    const int nt = K / 64, nIter = nt / 2;

    f32x4 acc[8][4] = {};
    bf16x8 a[4][2];

    auto stage = [&](int s) {
        if (s >= 4 * nt) return;
        const int tau = s >> 2, h = s & 3, hb = s & 1;
        const size_t rofs = (size_t)(hb * 128) * K + (size_t)tau * 64;
        if (h < 2) {
            const __bf16* g = gA + rofs;
            __bf16* l = Asm + (tau & 1) * 16384 + hb * 8192 + tid * 8;
            gload16(g, l);
            gload16(g + (size_t)64 * K, l + 4096);
        } else {
            const __bf16* g = gB + rofs;
            __bf16* l = Bsm + (tau & 1) * 16384 + hb * 8192 + tid * 8;
            gload16(g, l);
            gload16(g + (size_t)64 * K, l + 4096);
        }
    };

    // prologue: tile0 (4 halves) + A-top(1)
    stage(0); stage(1); stage(2); stage(3); stage(4);
    asm volatile("s_waitcnt vmcnt(2)" ::: "memory");
    __builtin_amdgcn_s_barrier();

    for (int i = 0; i < nIter; ++i) {
        const bool last = (i == nIter - 1);
#pragma unroll
        for (int p = 0; p < 8; ++p) {
            const int q = p & 3, cbuf = p >> 2;
            const __bf16* As = Asm + cbuf * 16384;
            const __bf16* Bs = Bsm + cbuf * 16384;
            bf16x8 b[2][2];
            if ((q & 1) == 0) {   // A-frags read at q=0,2; reused at q=1,3
#pragma unroll
                for (int mf = 0; mf < 4; ++mf) {
                    const int r = wm * 128 + (q >> 1) * 64 + mf * 16 + lrow;
                    a[mf][0] = *reinterpret_cast<const bf16x8*>(&As[r * 64 + aslot0]);
                    a[mf][1] = *reinterpret_cast<const bf16x8*>(&As[r * 64 + aslot1]);
                }
            }
#pragma unroll
            for (int nf = 0; nf < 2; ++nf) {
                const int r = wn * 64 + (q & 1) * 32 + nf * 16 + lrow;
                b[nf][0] = *reinterpret_cast<const bf16x8*>(&Bs[r * 64 + aslot0]);
                b[nf][1] = *reinterpret_cast<const bf16x8*>(&Bs[r * 64 + aslot1]);
            }
            stage(8 * i + p + 5);
            if (p == 3) {   // publish odd tile for p4..p7
                if (last) asm volatile("s_waitcnt vmcnt(0)" ::: "memory");
                else      asm volatile("s_waitcnt vmcnt(2)" ::: "memory");
            } else if (p == 7 && !last) {  // publish next even tile
                asm volatile("s_waitcnt vmcnt(2)" ::: "memory");
            }
            __builtin_amdgcn_s_barrier();
            asm volatile("s_waitcnt lgkmcnt(0)" ::: "memory");
            __builtin_amdgcn_sched_barrier(0);
            __builtin_amdgcn_s_setprio(1);
#pragma unroll
            for (int mf = 0; mf < 4; ++mf)
#pragma unroll
                for (int nf = 0; nf < 2; ++nf)
#pragma unroll
                    for (int kk = 0; kk < 2; ++kk)
                        acc[(q >> 1) * 4 + mf][(q & 1) * 2 + nf] =
                            __builtin_amdgcn_mfma_f32_16x16x32_bf16(
                                a[mf][kk], b[nf][kk],
                                acc[(q >> 1) * 4 + mf][(q & 1) * 2 + nf], 0, 0, 0);
            __builtin_amdgcn_s_setprio(0);
            __builtin_amdgcn_s_barrier();
        }
    }
#pragma unroll
    for (int Mi = 0; Mi < 8; ++Mi)
#pragma unroll
        for (int Ni = 0; Ni < 4; ++Ni)
#pragma unroll
            for (int j = 0; j < 4; ++j) {
                const size_t r = brow + wm * 128 + Mi * 16 + lkg * 4 + j;
                const size_t c = bcol + wn * 64 + Ni * 16 + lrow;
                C[r * N + c] = (__bf16)acc[Mi][Ni][j];
            }
}

// ---------------- GEMM 128x128 2-phase dbuf (kept for O-proj, splitK2) -------
template <int OUT_BF16>
__global__ __launch_bounds__(256) void gemm_bt(const __bf16* __restrict__ A,
                                               const __bf16* __restrict__ B,
                                               void* __restrict__ C0,
                                               void* __restrict__ C1,
                                               const int M, const int N, const int K,
                                               const int klen) {
    __shared__ __bf16 As0[128 * 64];
    __shared__ __bf16 Bs0[128 * 64];
    __shared__ __bf16 As1[128 * 64];
    __shared__ __bf16 Bs1[128 * 64];
    const int tid = threadIdx.x;
    const int lane = tid & 63;
    const int wave = tid >> 6;
    const int bn = blockIdx.x, bm = blockIdx.y;
    const int kbeg = blockIdx.z * klen;
    const int brow = bm * 128, bcol = bn * 128;
    const int wr = wave >> 1, wc = wave & 1;
    const int lrow = lane & 15, lkg = lane >> 4;
    const int srow_in = lane >> 3;
    const int scol = (lane & 7) * 8;
    f32x4 acc[4][4] = {};

    auto stage = [&](int k0, __bf16* as, __bf16* bs) {
#pragma unroll
        for (int r = 0; r < 4; ++r) {
            const int chunk = r * 4 + wave;
            const int row = chunk * 8 + srow_in;
            gload16(&A[(size_t)(brow + row) * K + k0 + scol], as + chunk * 512);
            gload16(&B[(size_t)(bcol + row) * K + k0 + scol], bs + chunk * 512);
        }
    };
    auto compute = [&](const __bf16* as, const __bf16* bs) {
#pragma unroll
        for (int kk = 0; kk < 2; ++kk) {
            bf16x8 a[4], bfr[4];
#pragma unroll
            for (int m = 0; m < 4; ++m)
                a[m] = *reinterpret_cast<const bf16x8*>(&as[(wr * 64 + m * 16 + lrow) * 64 + kk * 32 + lkg * 8]);
#pragma unroll
            for (int n = 0; n < 4; ++n)
                bfr[n] = *reinterpret_cast<const bf16x8*>(&bs[(wc * 64 + n * 16 + lrow) * 64 + kk * 32 + lkg * 8]);
#pragma unroll
            for (int m = 0; m < 4; ++m)
#pragma unroll
                for (int n = 0; n < 4; ++n)
                    acc[m][n] = __builtin_amdgcn_mfma_f32_16x16x32_bf16(a[m], bfr[n], acc[m][n], 0, 0, 0);
        }
    };

    const int nt = klen / 64;
    stage(kbeg, As0, Bs0);
    asm volatile("s_waitcnt vmcnt(0)" ::: "memory");
    __syncthreads();
    int t = 0;
    for (; t + 2 < nt; t += 2) {
        stage(kbeg + (t + 1) * 64, As1, Bs1);
        compute(As0, Bs0);
        asm volatile("s_waitcnt vmcnt(0)" ::: "memory");
        __syncthreads();
        stage(kbeg + (t + 2) * 64, As0, Bs0);
        compute(As1, Bs1);
        asm volatile("s_waitcnt vmcnt(0)" ::: "memory");
        __syncthreads();
    }
    stage(kbeg + (t + 1) * 64, As1, Bs1);
    compute(As0, Bs0);
    asm volatile("s_waitcnt vmcnt(0)" ::: "memory");
    __syncthreads();
    compute(As1, Bs1);

    void* C = blockIdx.z == 0 ? C0 : C1;
#pragma unroll
    for (int m = 0; m < 4; ++m)
#pragma unroll
        for (int n = 0; n < 4; ++n)
#pragma unroll
            for (int j = 0; j < 4; ++j) {
                const size_t r = brow + wr * 64 + m * 16 + lkg * 4 + j;
                const size_t c = bcol + wc * 64 + n * 16 + lrow;
                if (OUT_BF16)
                    ((__bf16*)C)[r * N + c] = (__bf16)acc[m][n][j];
                else
                    ((float*)C)[r * N + c] = acc[m][n][j];
            }
}

// ---------------- per-token RMSNorm + RoPE + paged cache scatter ----------------
__global__ __launch_bounds__(256) void norm_rope_cache(
    __bf16* __restrict__ qkv, const float* __restrict__ cosT, const float* __restrict__ sinT,
    const float* __restrict__ qw, const float* __restrict__ kw,
    const int* __restrict__ ptab, float* __restrict__ cacheK, float* __restrict__ cacheV) {
    const int t = blockIdx.x;
    const int b = t >> 10, s = t & 1023;
    const int wave = threadIdx.x >> 6, lane = threadIdx.x & 63;
    __bf16* row = qkv + (size_t)t * 5120;
    const float c = cosT[s * 128 + lane];   // cos[d+64] == cos[d]
    const float sn = sinT[s * 128 + lane];
    const int page = ptab[b * 32 + (s >> 5)];
    const int so = s & 31;
    const float wq0 = qw[lane], wq1 = qw[lane + 64];
#pragma unroll
    for (int i = 0; i < 8; ++i) {
        const int h = wave * 8 + i;
        float x0 = (float)row[h * 128 + lane];
        float x1 = (float)row[h * 128 + 64 + lane];
        float ss = x0 * x0 + x1 * x1;
        for (int off = 32; off; off >>= 1) ss += __shfl_xor(ss, off);
        const float rs = rsqrtf(ss * (1.0f / 128.0f) + 1e-6f);
        const float y0 = x0 * rs * wq0, y1 = x1 * rs * wq1;
        row[h * 128 + lane]      = (__bf16)(y0 * c - y1 * sn);
        row[h * 128 + 64 + lane] = (__bf16)(y1 * c + y0 * sn);
    }
    {
        const int h = wave;
        float x0 = (float)row[4096 + h * 128 + lane];
        float x1 = (float)row[4096 + h * 128 + 64 + lane];
        float ss = x0 * x0 + x1 * x1;
        for (int off = 32; off; off >>= 1) ss += __shfl_xor(ss, off);
        const float rs = rsqrtf(ss * (1.0f / 128.0f) + 1e-6f);
        const float y0 = x0 * rs * kw[lane], y1 = x1 * rs * kw[lane + 64];
        const float o0 = y0 * c - y1 * sn, o1 = y1 * c + y0 * sn;
        row[4096 + h * 128 + lane]      = (__bf16)o0;
        row[4096 + h * 128 + 64 + lane] = (__bf16)o1;
        float* ck = cacheK + (((size_t)page * 4 + h) * 32 + so) * 128;
        ck[lane] = o0; ck[lane + 64] = o1;
        const float v0 = (float)row[4608 + h * 128 + lane];
        const float v1 = (float)row[4608 + h * 128 + 64 + lane];
        float* cv = cacheV + (((size_t)page * 4 + h) * 32 + so) * 128;
        cv[lane] = v0; cv[lane + 64] = v1;
    }
}

// ---------------- flash attention, causal GQA, shared K/V staging ----------------
__global__ __launch_bounds__(512) void attn_fwd(const __bf16* __restrict__ qkv,
                                                __bf16* __restrict__ out) {
    constexpr int LVT = 72, LPT = 72;
    __shared__ __bf16 Ks[64 * 128];
    __shared__ __bf16 Vt[128 * LVT];
    __shared__ __bf16 Ps[8 * 16 * LPT];
    const int qb = 63 - blockIdx.x;
    const int kvg = blockIdx.y, b = blockIdx.z;
    const int tid = threadIdx.x, wave = tid >> 6, lane = tid & 63;
    const int lrow = lane & 15, lkg = lane >> 4;
    const int h = kvg * 8 + wave;
    const size_t base = (size_t)b * 1024 * 5120;
    const int kofs = 4096 + kvg * 128, vofs = 4608 + kvg * 128;
    const int qrow0 = qb * 16;

    bf16x8 aq[4];
#pragma unroll
    for (int kc = 0; kc < 4; ++kc)
        aq[kc] = *reinterpret_cast<const bf16x8*>(
            &qkv[base + (size_t)(qrow0 + lrow) * 5120 + h * 128 + kc * 32 + lkg * 8]);

    f32x4 acc[8] = {};
    float m_i = -1e30f, l_i = 0.f;
    const int nt = qb / 4 + 1;
    __bf16* Pw = &Ps[wave * 16 * LPT];
    const int swz = lrow & 7;

    for (int t = 0; t < nt; ++t) {
        const int kv0 = t * 64;
        __syncthreads();
#pragma unroll
        for (int c = 0; c < 2; ++c) {
            const int chunk = c * 8 + wave;
            const int row = chunk * 4 + (lane >> 4);
            const int gslot = (lane & 15) ^ (row & 7);
            gload16(&qkv[base + (size_t)(kv0 + row) * 5120 + kofs + gslot * 8],
                    &Ks[chunk * 512]);
        }
#pragma unroll
        for (int r = 0; r < 2; ++r) {
            const int d0 = (wave + r * 8) * 8;
            uint4 vv = *reinterpret_cast<const uint4*>(
                &qkv[base + (size_t)(kv0 + lane) * 5120 + vofs + d0]);
            const __bf16* pv = reinterpret_cast<const __bf16*>(&vv);
#pragma unroll
            for (int j = 0; j < 8; ++j) Vt[(d0 + j) * LVT + lane] = pv[j];
        }
        __syncthreads();

        f32x4 st[4] = {};
#pragma unroll
        for (int kc = 0; kc < 4; ++kc)
#pragma unroll
            for (int f = 0; f < 4; ++f) {
                bf16x8 ak = *reinterpret_cast<const bf16x8*>(
                    &Ks[(f * 16 + lrow) * 128 + ((kc * 4 + lkg) ^ swz) * 8]);
                st[f] = __builtin_amdgcn_mfma_f32_16x16x32_bf16(ak, aq[kc], st[f], 0, 0, 0);
            }

        const int qpos = qrow0 + lrow;
        float sv[16];
        float pmax = -1e30f;
#pragma unroll
        for (int f = 0; f < 4; ++f)
#pragma unroll
            for (int j = 0; j < 4; ++j) {
                const int kvpos = kv0 + f * 16 + lkg * 4 + j;
                float x = st[f][j] * 0.08838834764831845f;
                if (kvpos > qpos) x = -1e30f;
                sv[f * 4 + j] = x;
                pmax = fmaxf(pmax, x);
            }
        pmax = fmaxf(pmax, __shfl_xor(pmax, 16));
        pmax = fmaxf(pmax, __shfl_xor(pmax, 32));
        const float m_new = fmaxf(m_i, pmax);
        const float sf = __expf(m_i - m_new);
        float ladd = 0.f;
#pragma unroll
        for (int f = 0; f < 4; ++f) {
            bf16x4 pb;
#pragma unroll
            for (int j = 0; j < 4; ++j) {
                const float p = __expf(sv[f * 4 + j] - m_new);
                ladd += p;
                pb[j] = (__bf16)p;
            }
            *reinterpret_cast<bf16x4*>(&Pw[lrow * LPT + f * 16 + lkg * 4]) = pb;
        }
        ladd += __shfl_xor(ladd, 16);
        ladd += __shfl_xor(ladd, 32);
        l_i = l_i * sf + ladd;
        m_i = m_new;
        float sfj[4];
#pragma unroll
        for (int j = 0; j < 4; ++j) sfj[j] = __shfl(sf, lkg * 4 + j);
#pragma unroll
        for (int f = 0; f < 8; ++f)
#pragma unroll
            for (int j = 0; j < 4; ++j) acc[f][j] *= sfj[j];

#pragma unroll
        for (int kk = 0; kk < 2; ++kk) {
            bf16x8 ap = *reinterpret_cast<const bf16x8*>(&Pw[lrow * LPT + kk * 32 + lkg * 8]);
#pragma unroll
            for (int f = 0; f < 8; ++f) {
                bf16x8 bv = *reinterpret_cast<const bf16x8*>(
                    &Vt[(f * 16 + lrow) * LVT + kk * 32 + lkg * 8]);
                acc[f] = __builtin_amdgcn_mfma_f32_16x16x32_bf16(ap, bv, acc[f], 0, 0, 0);
            }
        }
    }
    float linv[4];
#pragma unroll
    for (int j = 0; j < 4; ++j) linv[j] = 1.0f / __shfl(l_i, lkg * 4 + j);
#pragma unroll
    for (int f = 0; f < 8; ++f)
#pragma unroll
        for (int j = 0; j < 4; ++j) {
            const size_t r = (size_t)b * 1024 + qrow0 + lkg * 4 + j;
            out[r * 4096 + h * 128 + f * 16 + lrow] = (__bf16)(acc[f][j] * linv[j]);
        }
}

// ---------------------------------------------------------------------------
extern "C" void kernel_launch(void* const* d_in, const int* in_sizes, int n_in,
                              void* d_out, int out_size, void* d_ws, size_t ws_size,
                              hipStream_t stream) {
    const float* hidden = (const float*)d_in[0];
    const float* wq = (const float*)d_in[1];
    const float* wk = (const float*)d_in[2];
    const float* wv = (const float*)d_in[3];
    const float* wo = (const float*)d_in[4];
    const float* qnw = (const float*)d_in[5];
    const float* knw = (const float*)d_in[6];
    const float* cosT = (const float*)d_in[7];
    const float* sinT = (const float*)d_in[8];
    const int* ptab = (const int*)d_in[9];

    float* outp = (float*)d_out;                 // (2,1024,2048)
    float* cacheK = outp + 4194304;              // (128,4,32,128)
    float* cacheV = cacheK + 2097152;

    char* ws = (char*)d_ws;
    __bf16* hbf    = (__bf16*)ws;                       // 2048x2048
    __bf16* w1bf   = (__bf16*)(ws + 8388608);           // 5120x2048 (wq|wk|wv)
    __bf16* wobf   = (__bf16*)(ws + 29360128);          // 2048x4096
    __bf16* qkvbf  = (__bf16*)(ws + 46137344);          // 2048x5120
    __bf16* attnbf = (__bf16*)ws;                       // 2048x4096 (overlay: hbf/w1bf dead)
    float*  opart  = (float*)(ws + 46137344);           // 2048x2048 f32 (overlay: qkvbf dead)

    // one fused conversion launch: hidden, wq, wk, wv, wo
    cvt5<<<22528, 256, 0, stream>>>(hidden, wq, wk, wv, wo,
                                    hbf, w1bf, w1bf + (size_t)4096 * 2048,
                                    w1bf + (size_t)4608 * 2048, wobf);

    // QKV projection: (2048x2048) @ (5120x2048)^T -> qkvbf bf16, 8-phase 256^2
    gemm256<<<160, 512, 0, stream>>>(hbf, w1bf, qkvbf, 2048, 5120, 2048);

    hipMemsetAsync(cacheK, 0, (size_t)4194304 * 4, stream);
    norm_rope_cache<<<2048, 256, 0, stream>>>(qkvbf, cosT, sinT, qnw, knw, ptab, cacheK, cacheV);

    attn_fwd<<<dim3(64, 4, 2), 512, 0, stream>>>(qkvbf, attnbf);

    // out projection, split-K2: (2048x4096) @ (2048x4096)^T -> f32
    gemm_bt<0><<<dim3(16, 16, 2), 256, 0, stream>>>(attnbf, wobf, outp, opart,
                                                    2048, 2048, 4096, 2048);
    reduce_add<<<2048, 256, 0, stream>>>(outp, opart, 4194304 / 4);
}

// Round 5
// 206.557 us; speedup vs baseline: 1.3591x; 1.0513x over previous
//
#include <hip/hip_runtime.h>
#include <hip/hip_bf16.h>

// ---------------------------------------------------------------------------
// Qwen3 attention block on MI355X, bf16 MFMA pipeline:
//   cvt5 -> gemm256 8-phase (QKV) -> norm+rope+cache
//   -> flash attn (paired q-tiles, dbuf K/V, counted vmcnt)
//   -> gemm_bt 2-phase splitK2 (O) -> reduce
// Shapes: B=2 S=1024 HID=2048 H=32 KV=4 D=128; qkv row = 5120
// ---------------------------------------------------------------------------

typedef __attribute__((ext_vector_type(8))) __bf16 bf16x8;
typedef __attribute__((ext_vector_type(4))) __bf16 bf16x4;
typedef __attribute__((ext_vector_type(4))) float f32x4;

__device__ __forceinline__ void gload16(const void* g, void* l) {
    __builtin_amdgcn_global_load_lds((const __attribute__((address_space(1))) void*)g,
                                     (__attribute__((address_space(3))) void*)l, 16, 0, 0);
}

// ---------------- fused fp32 -> bf16 convert, 5 segments, 1 f4/thread -------
__global__ __launch_bounds__(256) void cvt5(const float* __restrict__ s0, const float* __restrict__ s1,
                                            const float* __restrict__ s2, const float* __restrict__ s3,
                                            const float* __restrict__ s4,
                                            __bf16* __restrict__ d0, __bf16* __restrict__ d1,
                                            __bf16* __restrict__ d2, __bf16* __restrict__ d3,
                                            __bf16* __restrict__ d4) {
    const int b = blockIdx.x;
    const float* src; __bf16* dst; int off;
    if (b < 4096)       { src = s0; dst = d0; off = b; }
    else if (b < 12288) { src = s1; dst = d1; off = b - 4096; }
    else if (b < 13312) { src = s2; dst = d2; off = b - 12288; }
    else if (b < 14336) { src = s3; dst = d3; off = b - 13312; }
    else                { src = s4; dst = d4; off = b - 14336; }
    const int i = off * 256 + threadIdx.x;
    float4 v = reinterpret_cast<const float4*>(src)[i];
    bf16x4 o = {(__bf16)v.x, (__bf16)v.y, (__bf16)v.z, (__bf16)v.w};
    reinterpret_cast<bf16x4*>(dst)[i] = o;
}

// ---------------- o[i] += p[i] (split-K reduce) ----------------
__global__ __launch_bounds__(256) void reduce_add(float* __restrict__ o,
                                                  const float* __restrict__ p, int n4) {
    int i = blockIdx.x * 256 + threadIdx.x;
    int stride = gridDim.x * 256;
    for (; i < n4; i += stride) {
        float4 a = reinterpret_cast<float4*>(o)[i];
        float4 b = reinterpret_cast<const float4*>(p)[i];
        a.x += b.x; a.y += b.y; a.z += b.z; a.w += b.w;
        reinterpret_cast<float4*>(o)[i] = a;
    }
}

// ---------------- 256x256 8-phase GEMM (QKV projection) ----------------
__global__ __launch_bounds__(512, 2) void gemm256(const __bf16* __restrict__ A,
                                                  const __bf16* __restrict__ B,
                                                  __bf16* __restrict__ C,
                                                  const int M, const int N, const int K) {
    __shared__ __bf16 Asm[2 * 256 * 64];
    __shared__ __bf16 Bsm[2 * 256 * 64];
    const int tid = threadIdx.x, lane = tid & 63, wave = tid >> 6;
    const int wm = wave >> 2, wn = wave & 3;
    const int lrow = lane & 15, lkg = lane >> 4;
    const int nbn = N >> 8;
    const int swz = ((int)blockIdx.x & 7) * ((int)gridDim.x >> 3) + ((int)blockIdx.x >> 3);
    const int bm = swz / nbn, bn = swz % nbn;
    const int brow = bm * 256, bcol = bn * 256;
    const int row0 = tid >> 3;
    const int scol_sw = ((tid & 7) ^ (row0 & 7)) * 8;
    const __bf16* gA = A + (size_t)(brow + row0) * K + scol_sw;
    const __bf16* gB = B + (size_t)(bcol + row0) * K + scol_sw;
    const int aslot0 = (lkg ^ (lrow & 7)) * 8;
    const int aslot1 = ((4 + lkg) ^ (lrow & 7)) * 8;
    const int nt = K / 64, nIter = nt / 2;

    f32x4 acc[8][4] = {};
    bf16x8 a[4][2];

    auto stage = [&](int s) {
        if (s >= 4 * nt) return;
        const int tau = s >> 2, h = s & 3, hb = s & 1;
        const size_t rofs = (size_t)(hb * 128) * K + (size_t)tau * 64;
        if (h < 2) {
            const __bf16* g = gA + rofs;
            __bf16* l = Asm + (tau & 1) * 16384 + hb * 8192 + tid * 8;
            gload16(g, l);
            gload16(g + (size_t)64 * K, l + 4096);
        } else {
            const __bf16* g = gB + rofs;
            __bf16* l = Bsm + (tau & 1) * 16384 + hb * 8192 + tid * 8;
            gload16(g, l);
            gload16(g + (size_t)64 * K, l + 4096);
        }
    };

    stage(0); stage(1); stage(2); stage(3); stage(4);
    asm volatile("s_waitcnt vmcnt(2)" ::: "memory");
    __builtin_amdgcn_s_barrier();

    for (int i = 0; i < nIter; ++i) {
        const bool last = (i == nIter - 1);
#pragma unroll
        for (int p = 0; p < 8; ++p) {
            const int q = p & 3, cbuf = p >> 2;
            const __bf16* As = Asm + cbuf * 16384;
            const __bf16* Bs = Bsm + cbuf * 16384;
            bf16x8 b[2][2];
            if ((q & 1) == 0) {
#pragma unroll
                for (int mf = 0; mf < 4; ++mf) {
                    const int r = wm * 128 + (q >> 1) * 64 + mf * 16 + lrow;
                    a[mf][0] = *reinterpret_cast<const bf16x8*>(&As[r * 64 + aslot0]);
                    a[mf][1] = *reinterpret_cast<const bf16x8*>(&As[r * 64 + aslot1]);
                }
            }
#pragma unroll
            for (int nf = 0; nf < 2; ++nf) {
                const int r = wn * 64 + (q & 1) * 32 + nf * 16 + lrow;
                b[nf][0] = *reinterpret_cast<const bf16x8*>(&Bs[r * 64 + aslot0]);
                b[nf][1] = *reinterpret_cast<const bf16x8*>(&Bs[r * 64 + aslot1]);
            }
            stage(8 * i + p + 5);
            if (p == 3) {
                if (last) asm volatile("s_waitcnt vmcnt(0)" ::: "memory");
                else      asm volatile("s_waitcnt vmcnt(2)" ::: "memory");
            } else if (p == 7 && !last) {
                asm volatile("s_waitcnt vmcnt(2)" ::: "memory");
            }
            __builtin_amdgcn_s_barrier();
            asm volatile("s_waitcnt lgkmcnt(0)" ::: "memory");
            __builtin_amdgcn_sched_barrier(0);
            __builtin_amdgcn_s_setprio(1);
#pragma unroll
            for (int mf = 0; mf < 4; ++mf)
#pragma unroll
                for (int nf = 0; nf < 2; ++nf)
#pragma unroll
                    for (int kk = 0; kk < 2; ++kk)
                        acc[(q >> 1) * 4 + mf][(q & 1) * 2 + nf] =
                            __builtin_amdgcn_mfma_f32_16x16x32_bf16(
                                a[mf][kk], b[nf][kk],
                                acc[(q >> 1) * 4 + mf][(q & 1) * 2 + nf], 0, 0, 0);
            __builtin_amdgcn_s_setprio(0);
            __builtin_amdgcn_s_barrier();
        }
    }
#pragma unroll
    for (int Mi = 0; Mi < 8; ++Mi)
#pragma unroll
        for (int Ni = 0; Ni < 4; ++Ni)
#pragma unroll
            for (int j = 0; j < 4; ++j) {
                const size_t r = brow + wm * 128 + Mi * 16 + lkg * 4 + j;
                const size_t c = bcol + wn * 64 + Ni * 16 + lrow;
                C[r * N + c] = (__bf16)acc[Mi][Ni][j];
            }
}

// ---------------- GEMM 128x128 2-phase dbuf (O-proj, splitK2) ----------------
template <int OUT_BF16>
__global__ __launch_bounds__(256) void gemm_bt(const __bf16* __restrict__ A,
                                               const __bf16* __restrict__ B,
                                               void* __restrict__ C0,
                                               void* __restrict__ C1,
                                               const int M, const int N, const int K,
                                               const int klen) {
    __shared__ __bf16 As0[128 * 64];
    __shared__ __bf16 Bs0[128 * 64];
    __shared__ __bf16 As1[128 * 64];
    __shared__ __bf16 Bs1[128 * 64];
    const int tid = threadIdx.x;
    const int lane = tid & 63;
    const int wave = tid >> 6;
    const int bn = blockIdx.x, bm = blockIdx.y;
    const int kbeg = blockIdx.z * klen;
    const int brow = bm * 128, bcol = bn * 128;
    const int wr = wave >> 1, wc = wave & 1;
    const int lrow = lane & 15, lkg = lane >> 4;
    const int srow_in = lane >> 3;
    const int scol = (lane & 7) * 8;
    f32x4 acc[4][4] = {};

    auto stage = [&](int k0, __bf16* as, __bf16* bs) {
#pragma unroll
        for (int r = 0; r < 4; ++r) {
            const int chunk = r * 4 + wave;
            const int row = chunk * 8 + srow_in;
            gload16(&A[(size_t)(brow + row) * K + k0 + scol], as + chunk * 512);
            gload16(&B[(size_t)(bcol + row) * K + k0 + scol], bs + chunk * 512);
        }
    };
    auto compute = [&](const __bf16* as, const __bf16* bs) {
#pragma unroll
        for (int kk = 0; kk < 2; ++kk) {
            bf16x8 a[4], bfr[4];
#pragma unroll
            for (int m = 0; m < 4; ++m)
                a[m] = *reinterpret_cast<const bf16x8*>(&as[(wr * 64 + m * 16 + lrow) * 64 + kk * 32 + lkg * 8]);
#pragma unroll
            for (int n = 0; n < 4; ++n)
                bfr[n] = *reinterpret_cast<const bf16x8*>(&bs[(wc * 64 + n * 16 + lrow) * 64 + kk * 32 + lkg * 8]);
#pragma unroll
            for (int m = 0; m < 4; ++m)
#pragma unroll
                for (int n = 0; n < 4; ++n)
                    acc[m][n] = __builtin_amdgcn_mfma_f32_16x16x32_bf16(a[m], bfr[n], acc[m][n], 0, 0, 0);
        }
    };

    const int nt = klen / 64;
    stage(kbeg, As0, Bs0);
    asm volatile("s_waitcnt vmcnt(0)" ::: "memory");
    __syncthreads();
    int t = 0;
    for (; t + 2 < nt; t += 2) {
        stage(kbeg + (t + 1) * 64, As1, Bs1);
        compute(As0, Bs0);
        asm volatile("s_waitcnt vmcnt(0)" ::: "memory");
        __syncthreads();
        stage(kbeg + (t + 2) * 64, As0, Bs0);
        compute(As1, Bs1);
        asm volatile("s_waitcnt vmcnt(0)" ::: "memory");
        __syncthreads();
    }
    stage(kbeg + (t + 1) * 64, As1, Bs1);
    compute(As0, Bs0);
    asm volatile("s_waitcnt vmcnt(0)" ::: "memory");
    __syncthreads();
    compute(As1, Bs1);

    void* C = blockIdx.z == 0 ? C0 : C1;
#pragma unroll
    for (int m = 0; m < 4; ++m)
#pragma unroll
        for (int n = 0; n < 4; ++n)
#pragma unroll
            for (int j = 0; j < 4; ++j) {
                const size_t r = brow + wr * 64 + m * 16 + lkg * 4 + j;
                const size_t c = bcol + wc * 64 + n * 16 + lrow;
                if (OUT_BF16)
                    ((__bf16*)C)[r * N + c] = (__bf16)acc[m][n][j];
                else
                    ((float*)C)[r * N + c] = acc[m][n][j];
            }
}

// ---------------- per-token RMSNorm + RoPE + paged cache scatter ----------------
__global__ __launch_bounds__(256) void norm_rope_cache(
    __bf16* __restrict__ qkv, const float* __restrict__ cosT, const float* __restrict__ sinT,
    const float* __restrict__ qw, const float* __restrict__ kw,
    const int* __restrict__ ptab, float* __restrict__ cacheK, float* __restrict__ cacheV) {
    const int t = blockIdx.x;
    const int b = t >> 10, s = t & 1023;
    const int wave = threadIdx.x >> 6, lane = threadIdx.x & 63;
    __bf16* row = qkv + (size_t)t * 5120;
    const float c = cosT[s * 128 + lane];   // cos[d+64] == cos[d]
    const float sn = sinT[s * 128 + lane];
    const int page = ptab[b * 32 + (s >> 5)];
    const int so = s & 31;
    const float wq0 = qw[lane], wq1 = qw[lane + 64];
#pragma unroll
    for (int i = 0; i < 8; ++i) {
        const int h = wave * 8 + i;
        float x0 = (float)row[h * 128 + lane];
        float x1 = (float)row[h * 128 + 64 + lane];
        float ss = x0 * x0 + x1 * x1;
        for (int off = 32; off; off >>= 1) ss += __shfl_xor(ss, off);
        const float rs = rsqrtf(ss * (1.0f / 128.0f) + 1e-6f);
        const float y0 = x0 * rs * wq0, y1 = x1 * rs * wq1;
        row[h * 128 + lane]      = (__bf16)(y0 * c - y1 * sn);
        row[h * 128 + 64 + lane] = (__bf16)(y1 * c + y0 * sn);
    }
    {
        const int h = wave;
        float x0 = (float)row[4096 + h * 128 + lane];
        float x1 = (float)row[4096 + h * 128 + 64 + lane];
        float ss = x0 * x0 + x1 * x1;
        for (int off = 32; off; off >>= 1) ss += __shfl_xor(ss, off);
        const float rs = rsqrtf(ss * (1.0f / 128.0f) + 1e-6f);
        const float y0 = x0 * rs * kw[lane], y1 = x1 * rs * kw[lane + 64];
        const float o0 = y0 * c - y1 * sn, o1 = y1 * c + y0 * sn;
        row[4096 + h * 128 + lane]      = (__bf16)o0;
        row[4096 + h * 128 + 64 + lane] = (__bf16)o1;
        float* ck = cacheK + (((size_t)page * 4 + h) * 32 + so) * 128;
        ck[lane] = o0; ck[lane + 64] = o1;
        const float v0 = (float)row[4608 + h * 128 + lane];
        const float v1 = (float)row[4608 + h * 128 + 64 + lane];
        float* cv = cacheV + (((size_t)page * 4 + h) * 32 + so) * 128;
        cv[lane] = v0; cv[lane + 64] = v1;
    }
}

// ---------------- flash attention, causal GQA ----------------
// grid (32,4,2) = 256 blocks = 1/CU. Block x handles q-tile pair (qa=x, 63-x):
// every block = exactly 17 MFMA-tiles (perfect balance). 8 waves = 8 heads of
// the kv-group; K/V staged once, shared by 8 heads x 2 q-frags.
// Double-buffered K (global_load_lds, source-swizzled) and V (reg-staged,
// T14 split: gload one tile early, ds_write after vmcnt(4)); counted vmcnt,
// raw s_barriers (2/tile). All LDS layouts XOR-swizzled (slot ^ row&7).
__global__ __launch_bounds__(512, 2) void attn_fwd(const __bf16* __restrict__ qkv,
                                                   __bf16* __restrict__ out) {
    __shared__ __bf16 Ks[2][64 * 128];     // 2 x 16KB
    __shared__ __bf16 Vs[2][128 * 64];     // 2 x 16KB, transposed [d][kv]
    __shared__ __bf16 Ps[8][2][16 * 64];   // per-wave P tiles, 32KB
    const int qa = blockIdx.x;             // 0..31
    const int qbig = 63 - qa;
    const int kvg = blockIdx.y, b = blockIdx.z;
    const int tid = threadIdx.x, wave = tid >> 6, lane = tid & 63;
    const int lrow = lane & 15, lkg = lane >> 4;
    const int h = kvg * 8 + wave;
    const size_t base = (size_t)b * 1024 * 5120;
    const int kofs = 4096 + kvg * 128, vofs = 4608 + kvg * 128;
    const int ntA = qa / 4 + 1, nt = qbig / 4 + 1;
    const int qposA = qa * 16 + lrow, qposB = qbig * 16 + lrow;
    const int rsw = lrow & 7;              // read-side row swizzle

    // Q fragments (B-operand), pre-scaled by 1/sqrt(D)
    bf16x8 aqA[4], aqB[4];
#pragma unroll
    for (int kc = 0; kc < 4; ++kc) {
        bf16x8 ta = *reinterpret_cast<const bf16x8*>(
            &qkv[base + (size_t)(qa * 16 + lrow) * 5120 + h * 128 + kc * 32 + lkg * 8]);
        bf16x8 tb = *reinterpret_cast<const bf16x8*>(
            &qkv[base + (size_t)(qbig * 16 + lrow) * 5120 + h * 128 + kc * 32 + lkg * 8]);
#pragma unroll
        for (int i = 0; i < 8; ++i) {
            ta[i] = (__bf16)((float)ta[i] * 0.08838834764831845f);
            tb[i] = (__bf16)((float)tb[i] * 0.08838834764831845f);
        }
        aqA[kc] = ta; aqB[kc] = tb;
    }

    f32x4 accA[8] = {}, accB[8] = {};       // O[q=lkg*4+j][d=f*16+lrow]
    float mA = -1e30f, lA = 0.f, mB = -1e30f, lB = 0.f;
    __bf16* PwA = &Ps[wave][0][0];
    __bf16* PwB = &Ps[wave][1][0];

    auto stageK = [&](int t, int buf) {     // 64x128 via global_load_lds x2
        const int kv0 = (t < nt) ? t * 64 : 0;
#pragma unroll
        for (int c = 0; c < 2; ++c) {
            const int chunk = c * 8 + wave;
            const int row = chunk * 4 + (lane >> 4);
            const int gslot = (lane & 15) ^ (row & 7);
            gload16(&qkv[base + (size_t)(kv0 + row) * 5120 + kofs + gslot * 8],
                    &Ks[buf][chunk * 512]);
        }
    };
    auto loadV = [&](int t, uint4 (&vr)[2]) {
        const int kv0 = (t < nt) ? t * 64 : 0;
#pragma unroll
        for (int r = 0; r < 2; ++r)
            vr[r] = *reinterpret_cast<const uint4*>(
                &qkv[base + (size_t)(kv0 + lane) * 5120 + vofs + wave * 16 + r * 8]);
    };
    auto writeV = [&](uint4 (&vr)[2], int buf) {
#pragma unroll
        for (int r = 0; r < 2; ++r) {
            const __bf16* pv = reinterpret_cast<const __bf16*>(&vr[r]);
#pragma unroll
            for (int j = 0; j < 8; ++j) {
                const int d = wave * 16 + r * 8 + j;
                Vs[buf][d * 64 + (((lane >> 3) ^ j) << 3) + (lane & 7)] = pv[j];
            }
        }
    };

    auto smax = [&](f32x4 (&st)[4], float& m_i, float& l_i, f32x4 (&acc)[8],
                    int qpos, int kv0, bool maskit, __bf16* Pw) {
        float sv[16]; float pmax = -1e30f;
#pragma unroll
        for (int f = 0; f < 4; ++f)
#pragma unroll
            for (int j = 0; j < 4; ++j) {
                float x = st[f][j];
                if (maskit) {
                    const int kvpos = kv0 + f * 16 + lkg * 4 + j;
                    if (kvpos > qpos) x = -1e30f;
                }
                sv[f * 4 + j] = x;
                pmax = fmaxf(pmax, x);
            }
        pmax = fmaxf(pmax, __shfl_xor(pmax, 16));
        pmax = fmaxf(pmax, __shfl_xor(pmax, 32));
        if (!__all(pmax - m_i <= 8.f)) {    // defer-max (T13)
            const float m_new = fmaxf(m_i, pmax);
            const float sf = __expf(m_i - m_new);
            m_i = m_new;
            l_i *= sf;
            float sfj[4];
#pragma unroll
            for (int j = 0; j < 4; ++j) sfj[j] = __shfl(sf, lkg * 4 + j);
#pragma unroll
            for (int f = 0; f < 8; ++f)
#pragma unroll
                for (int j = 0; j < 4; ++j) acc[f][j] *= sfj[j];
        }
        float ladd = 0.f;
#pragma unroll
        for (int f = 0; f < 4; ++f) {
            bf16x4 pb;
#pragma unroll
            for (int j = 0; j < 4; ++j) {
                const float p = __expf(sv[f * 4 + j] - m_i);
                ladd += p;
                pb[j] = (__bf16)p;
            }
            const int slot = (f * 2 + (lkg >> 1)) ^ rsw;
            *reinterpret_cast<bf16x4*>(&Pw[lrow * 64 + slot * 8 + (lkg & 1) * 4]) = pb;
        }
        ladd += __shfl_xor(ladd, 16);
        ladd += __shfl_xor(ladd, 32);
        l_i += ladd;
    };

    auto body = [&](int t, uint4 (&vcur)[2], uint4 (&vnext)[2]) {
        const int kbuf = t & 1;
        __builtin_amdgcn_s_barrier();               // B1: prior reads of buf^1 done
        asm volatile("" ::: "memory");
        loadV(t + 1, vnext);                        // 2 reg gloads (oldest of new 4)
        stageK(t + 1, kbuf ^ 1);                    // 2 lds gloads
        asm volatile("s_waitcnt vmcnt(4)" ::: "memory");  // tile-t K in LDS, V(t) in regs
        writeV(vcur, kbuf);
        asm volatile("s_waitcnt lgkmcnt(0)" ::: "memory");
        __builtin_amdgcn_s_barrier();               // B2: tile t published
        asm volatile("" ::: "memory");

        const bool doA = t < ntA;
        f32x4 stA[4] = {}, stB[4] = {};
#pragma unroll
        for (int kc = 0; kc < 4; ++kc)
#pragma unroll
            for (int f = 0; f < 4; ++f) {           // ak shared by both q-frags
                bf16x8 ak = *reinterpret_cast<const bf16x8*>(
                    &Ks[kbuf][(f * 16 + lrow) * 128 + (((kc * 4 + lkg) ^ rsw) << 3)]);
                stB[f] = __builtin_amdgcn_mfma_f32_16x16x32_bf16(ak, aqB[kc], stB[f], 0, 0, 0);
                if (doA)
                    stA[f] = __builtin_amdgcn_mfma_f32_16x16x32_bf16(ak, aqA[kc], stA[f], 0, 0, 0);
            }
        if (doA) smax(stA, mA, lA, accA, qposA, t * 64, t == ntA - 1, PwA);
        smax(stB, mB, lB, accB, qposB, t * 64, t == nt - 1, PwB);
#pragma unroll
        for (int kk = 0; kk < 2; ++kk) {            // bv shared by both q-frags
            const int pslot = ((kk * 4 + lkg) ^ rsw) << 3;
            bf16x8 apB = *reinterpret_cast<const bf16x8*>(&PwB[lrow * 64 + pslot]);
            bf16x8 apA;
            if (doA) apA = *reinterpret_cast<const bf16x8*>(&PwA[lrow * 64 + pslot]);
#pragma unroll
            for (int f = 0; f < 8; ++f) {
                bf16x8 bv = *reinterpret_cast<const bf16x8*>(
                    &Vs[kbuf][(f * 16 + lrow) * 64 + pslot]);
                accB[f] = __builtin_amdgcn_mfma_f32_16x16x32_bf16(apB, bv, accB[f], 0, 0, 0);
                if (doA)
                    accA[f] = __builtin_amdgcn_mfma_f32_16x16x32_bf16(apA, bv, accA[f], 0, 0, 0);
            }
        }
    };

    uint4 vrA[2], vrB[2];
    loadV(0, vrA);
    stageK(0, 0);
    for (int t = 0; t < nt; t += 2) {
        body(t, vrA, vrB);
        if (t + 1 < nt) body(t + 1, vrB, vrA);
    }
    asm volatile("s_waitcnt vmcnt(0)" ::: "memory");

    float linvA[4], linvB[4];
#pragma unroll
    for (int j = 0; j < 4; ++j) {
        linvA[j] = 1.0f / __shfl(lA, lkg * 4 + j);
        linvB[j] = 1.0f / __shfl(lB, lkg * 4 + j);
    }
#pragma unroll
    for (int f = 0; f < 8; ++f)
#pragma unroll
        for (int j = 0; j < 4; ++j) {
            out[((size_t)b * 1024 + qa * 16 + lkg * 4 + j) * 4096 + h * 128 + f * 16 + lrow] =
                (__bf16)(accA[f][j] * linvA[j]);
            out[((size_t)b * 1024 + qbig * 16 + lkg * 4 + j) * 4096 + h * 128 + f * 16 + lrow] =
                (__bf16)(accB[f][j] * linvB[j]);
        }
}

// ---------------------------------------------------------------------------
extern "C" void kernel_launch(void* const* d_in, const int* in_sizes, int n_in,
                              void* d_out, int out_size, void* d_ws, size_t ws_size,
                              hipStream_t stream) {
    const float* hidden = (const float*)d_in[0];
    const float* wq = (const float*)d_in[1];
    const float* wk = (const float*)d_in[2];
    const float* wv = (const float*)d_in[3];
    const float* wo = (const float*)d_in[4];
    const float* qnw = (const float*)d_in[5];
    const float* knw = (const float*)d_in[6];
    const float* cosT = (const float*)d_in[7];
    const float* sinT = (const float*)d_in[8];
    const int* ptab = (const int*)d_in[9];

    float* outp = (float*)d_out;                 // (2,1024,2048)
    float* cacheK = outp + 4194304;              // (128,4,32,128)
    float* cacheV = cacheK + 2097152;

    char* ws = (char*)d_ws;
    __bf16* hbf    = (__bf16*)ws;                       // 2048x2048
    __bf16* w1bf   = (__bf16*)(ws + 8388608);           // 5120x2048 (wq|wk|wv)
    __bf16* wobf   = (__bf16*)(ws + 29360128);          // 2048x4096
    __bf16* qkvbf  = (__bf16*)(ws + 46137344);          // 2048x5120
    __bf16* attnbf = (__bf16*)ws;                       // 2048x4096 (overlay: hbf/w1bf dead)
    float*  opart  = (float*)(ws + 46137344);           // 2048x2048 f32 (overlay: qkvbf dead)

    cvt5<<<22528, 256, 0, stream>>>(hidden, wq, wk, wv, wo,
                                    hbf, w1bf, w1bf + (size_t)4096 * 2048,
                                    w1bf + (size_t)4608 * 2048, wobf);

    // QKV projection: (2048x2048) @ (5120x2048)^T -> qkvbf bf16, 8-phase 256^2
    gemm256<<<160, 512, 0, stream>>>(hbf, w1bf, qkvbf, 2048, 5120, 2048);

    hipMemsetAsync(cacheK, 0, (size_t)4194304 * 4, stream);
    norm_rope_cache<<<2048, 256, 0, stream>>>(qkvbf, cosT, sinT, qnw, knw, ptab, cacheK, cacheV);

    attn_fwd<<<dim3(32, 4, 2), 512, 0, stream>>>(qkvbf, attnbf);

    // out projection, split-K2: (2048x4096) @ (2048x4096)^T -> f32
    gemm_bt<0><<<dim3(16, 16, 2), 256, 0, stream>>>(attnbf, wobf, outp, opart,
                                                    2048, 2048, 4096, 2048);
    reduce_add<<<2048, 256, 0, stream>>>(outp, opart, 4194304 / 4);
}

// Round 6
// 201.728 us; speedup vs baseline: 1.3916x; 1.0239x over previous
//
#include <hip/hip_runtime.h>
#include <hip/hip_bf16.h>

// ---------------------------------------------------------------------------
// Qwen3 attention block on MI355X, bf16 MFMA pipeline:
//   cvt5 -> gemm8p<5> (QKV, 256 blocks) -> norm+rope+cache
//   -> flash attn (paired q-tiles) -> gemm8p<4> splitK2 (O, 256 blocks) -> reduce
// Shapes: B=2 S=1024 HID=2048 H=32 KV=4 D=128; qkv row = 5120
// ---------------------------------------------------------------------------

typedef __attribute__((ext_vector_type(8))) __bf16 bf16x8;
typedef __attribute__((ext_vector_type(4))) __bf16 bf16x4;
typedef __attribute__((ext_vector_type(4))) float f32x4;

__device__ __forceinline__ void gload16(const void* g, void* l) {
    __builtin_amdgcn_global_load_lds((const __attribute__((address_space(1))) void*)g,
                                     (__attribute__((address_space(3))) void*)l, 16, 0, 0);
}

// ---------------- fused fp32 -> bf16 convert, 5 segments, 1 f4/thread -------
__global__ __launch_bounds__(256) void cvt5(const float* __restrict__ s0, const float* __restrict__ s1,
                                            const float* __restrict__ s2, const float* __restrict__ s3,
                                            const float* __restrict__ s4,
                                            __bf16* __restrict__ d0, __bf16* __restrict__ d1,
                                            __bf16* __restrict__ d2, __bf16* __restrict__ d3,
                                            __bf16* __restrict__ d4) {
    const int b = blockIdx.x;
    const float* src; __bf16* dst; int off;
    if (b < 4096)       { src = s0; dst = d0; off = b; }
    else if (b < 12288) { src = s1; dst = d1; off = b - 4096; }
    else if (b < 13312) { src = s2; dst = d2; off = b - 12288; }
    else if (b < 14336) { src = s3; dst = d3; off = b - 13312; }
    else                { src = s4; dst = d4; off = b - 14336; }
    const int i = off * 256 + threadIdx.x;
    float4 v = reinterpret_cast<const float4*>(src)[i];
    bf16x4 o = {(__bf16)v.x, (__bf16)v.y, (__bf16)v.z, (__bf16)v.w};
    reinterpret_cast<bf16x4*>(dst)[i] = o;
}

// ---------------- o[i] += p[i] (split-K reduce) ----------------
__global__ __launch_bounds__(256) void reduce_add(float* __restrict__ o,
                                                  const float* __restrict__ p, int n4) {
    int i = blockIdx.x * 256 + threadIdx.x;
    int stride = gridDim.x * 256;
    for (; i < n4; i += stride) {
        float4 a = reinterpret_cast<float4*>(o)[i];
        float4 b = reinterpret_cast<const float4*>(p)[i];
        a.x += b.x; a.y += b.y; a.z += b.z; a.w += b.w;
        reinterpret_cast<float4*>(o)[i] = a;
    }
}

// ---------------- 8-phase GEMM, BM=128, BN=NF*64, BK=64, 512 thr ----------------
// C[m][n] = sum_k A[m][k]*B[n][k].  8 waves = 2m x 4n; wave tile 64 x NF*16.
// Stage units = 64rows x 64cols (A: 2/tile, B: NF/tile); per-phase issue counts
// keep publish-point outstanding at exactly 2 -> vmcnt(2) at p3/p7 (vmcnt(0) last).
// Read-swizzle slot^(row&7), source pre-swizzled. kz (blockIdx/nTiles) = K-split.
template <int NF, int OUT_BF16>
__global__ __launch_bounds__(512, 2) void gemm8p(const __bf16* __restrict__ A,
                                                 const __bf16* __restrict__ B,
                                                 void* __restrict__ C0,
                                                 void* __restrict__ C1,
                                                 const int M, const int N, const int K,
                                                 const int nTiles, const int nbn,
                                                 const int klen) {
    __shared__ __bf16 Asm[2 * 128 * 64];
    __shared__ __bf16 Bsm[2 * NF * 64 * 64];
    const int tid = threadIdx.x, lane = tid & 63, wave = tid >> 6;
    const int wm = wave >> 2, wn = wave & 3;
    const int lrow = lane & 15, lkg = lane >> 4;
    const int rsw = lrow & 7;
    const int bid = blockIdx.x;
    const int kz = bid / nTiles, tile = bid % nTiles;
    const int tswz = (tile & 7) * (nTiles >> 3) + (tile >> 3);   // XCD swizzle
    const int bm = tswz / nbn, bn = tswz % nbn;
    const int brow = bm * 128, bcol = bn * (NF * 64);
    const int kbeg = kz * klen;
    const int row0 = tid >> 3;
    const int scol_sw = ((tid & 7) ^ (row0 & 7)) * 8;
    const __bf16* gA = A + (size_t)(brow + row0) * K + kbeg + scol_sw;
    const __bf16* gB = B + (size_t)(bcol + row0) * K + kbeg + scol_sw;
    const int slot0 = (lkg ^ rsw) * 8;
    const int slot1 = ((4 + lkg) ^ rsw) * 8;
    const int nt = klen / 64, nIter = nt / 2;

    f32x4 acc[4][NF] = {};
    bf16x8 areg[2], breg[NF];

    int su_t = 0, su_w = 0;
    auto stage1 = [&]() {
        if (su_t < nt) {
            const size_t ko = (size_t)su_t * 64;
            if (su_w < 2)
                gload16(gA + (size_t)(su_w * 64) * K + ko,
                        Asm + (su_t & 1) * 8192 + su_w * 4096 + tid * 8);
            else
                gload16(gB + (size_t)((su_w - 2) * 64) * K + ko,
                        Bsm + (su_t & 1) * (NF * 4096) + (su_w - 2) * 4096 + tid * 8);
        }
        if (++su_w == NF + 2) { su_w = 0; ++su_t; }
    };

    // prologue: tile0 fully + first 2 units of tile1
    for (int u = 0; u < NF + 4; ++u) stage1();
    asm volatile("s_waitcnt vmcnt(2)" ::: "memory");
    __builtin_amdgcn_s_barrier();

    for (int i = 0; i < nIter; ++i) {
        const bool last = (i == nIter - 1);
#pragma unroll
        for (int p = 0; p < 8; ++p) {
            const int q = p & 3, kk = q >> 1, mfh = q & 1, cbuf = p >> 2;
            const __bf16* As = Asm + cbuf * 8192;
            const __bf16* Bs = Bsm + cbuf * (NF * 4096);
            const int ks = kk ? slot1 : slot0;
            if (mfh == 0) {
#pragma unroll
                for (int nf = 0; nf < NF; ++nf)
                    breg[nf] = *reinterpret_cast<const bf16x8*>(
                        &Bs[(wn * (NF * 16) + nf * 16 + lrow) * 64 + ks]);
            }
#pragma unroll
            for (int mi = 0; mi < 2; ++mi)
                areg[mi] = *reinterpret_cast<const bf16x8*>(
                    &As[(wm * 64 + (mfh * 2 + mi) * 16 + lrow) * 64 + ks]);
            // staging issue: per-phase counts keep publish outstanding == 2
            const int cp = (NF == 5) ? ((q == 2) ? 1 : 2)
                                     : ((q == 1 || q == 2) ? 1 : 2);
            stage1();
            if (cp == 2) stage1();
            if (p == 3) {
                if (last) asm volatile("s_waitcnt vmcnt(0)" ::: "memory");
                else      asm volatile("s_waitcnt vmcnt(2)" ::: "memory");
            } else if (p == 7 && !last) {
                asm volatile("s_waitcnt vmcnt(2)" ::: "memory");
            }
            __builtin_amdgcn_s_barrier();
            asm volatile("s_waitcnt lgkmcnt(0)" ::: "memory");
            __builtin_amdgcn_sched_barrier(0);
            __builtin_amdgcn_s_setprio(1);
#pragma unroll
            for (int mi = 0; mi < 2; ++mi)
#pragma unroll
                for (int nf = 0; nf < NF; ++nf)
                    acc[mfh * 2 + mi][nf] = __builtin_amdgcn_mfma_f32_16x16x32_bf16(
                        areg[mi], breg[nf], acc[mfh * 2 + mi][nf], 0, 0, 0);
            __builtin_amdgcn_s_setprio(0);
            __builtin_amdgcn_s_barrier();
        }
    }

    void* C = (kz == 0) ? C0 : C1;
#pragma unroll
    for (int mi = 0; mi < 4; ++mi)
#pragma unroll
        for (int nf = 0; nf < NF; ++nf)
#pragma unroll
            for (int j = 0; j < 4; ++j) {
                const size_t r = brow + wm * 64 + mi * 16 + lkg * 4 + j;
                const size_t c = bcol + wn * (NF * 16) + nf * 16 + lrow;
                if (OUT_BF16)
                    ((__bf16*)C)[r * N + c] = (__bf16)acc[mi][nf][j];
                else
                    ((float*)C)[r * N + c] = acc[mi][nf][j];
            }
}

// ---------------- per-token RMSNorm + RoPE + paged cache scatter ----------------
__global__ __launch_bounds__(256) void norm_rope_cache(
    __bf16* __restrict__ qkv, const float* __restrict__ cosT, const float* __restrict__ sinT,
    const float* __restrict__ qw, const float* __restrict__ kw,
    const int* __restrict__ ptab, float* __restrict__ cacheK, float* __restrict__ cacheV) {
    const int t = blockIdx.x;
    const int b = t >> 10, s = t & 1023;
    const int wave = threadIdx.x >> 6, lane = threadIdx.x & 63;
    __bf16* row = qkv + (size_t)t * 5120;
    const float c = cosT[s * 128 + lane];   // cos[d+64] == cos[d]
    const float sn = sinT[s * 128 + lane];
    const int page = ptab[b * 32 + (s >> 5)];
    const int so = s & 31;
    const float wq0 = qw[lane], wq1 = qw[lane + 64];
#pragma unroll
    for (int i = 0; i < 8; ++i) {
        const int h = wave * 8 + i;
        float x0 = (float)row[h * 128 + lane];
        float x1 = (float)row[h * 128 + 64 + lane];
        float ss = x0 * x0 + x1 * x1;
        for (int off = 32; off; off >>= 1) ss += __shfl_xor(ss, off);
        const float rs = rsqrtf(ss * (1.0f / 128.0f) + 1e-6f);
        const float y0 = x0 * rs * wq0, y1 = x1 * rs * wq1;
        row[h * 128 + lane]      = (__bf16)(y0 * c - y1 * sn);
        row[h * 128 + 64 + lane] = (__bf16)(y1 * c + y0 * sn);
    }
    {
        const int h = wave;
        float x0 = (float)row[4096 + h * 128 + lane];
        float x1 = (float)row[4096 + h * 128 + 64 + lane];
        float ss = x0 * x0 + x1 * x1;
        for (int off = 32; off; off >>= 1) ss += __shfl_xor(ss, off);
        const float rs = rsqrtf(ss * (1.0f / 128.0f) + 1e-6f);
        const float y0 = x0 * rs * kw[lane], y1 = x1 * rs * kw[lane + 64];
        const float o0 = y0 * c - y1 * sn, o1 = y1 * c + y0 * sn;
        row[4096 + h * 128 + lane]      = (__bf16)o0;
        row[4096 + h * 128 + 64 + lane] = (__bf16)o1;
        float* ck = cacheK + (((size_t)page * 4 + h) * 32 + so) * 128;
        ck[lane] = o0; ck[lane + 64] = o1;
        const float v0 = (float)row[4608 + h * 128 + lane];
        const float v1 = (float)row[4608 + h * 128 + 64 + lane];
        float* cv = cacheV + (((size_t)page * 4 + h) * 32 + so) * 128;
        cv[lane] = v0; cv[lane + 64] = v1;
    }
}

// ---------------- flash attention, causal GQA (r5 structure, unchanged) ----------
__global__ __launch_bounds__(512, 2) void attn_fwd(const __bf16* __restrict__ qkv,
                                                   __bf16* __restrict__ out) {
    __shared__ __bf16 Ks[2][64 * 128];
    __shared__ __bf16 Vs[2][128 * 64];
    __shared__ __bf16 Ps[8][2][16 * 64];
    const int qa = blockIdx.x;
    const int qbig = 63 - qa;
    const int kvg = blockIdx.y, b = blockIdx.z;
    const int tid = threadIdx.x, wave = tid >> 6, lane = tid & 63;
    const int lrow = lane & 15, lkg = lane >> 4;
    const int h = kvg * 8 + wave;
    const size_t base = (size_t)b * 1024 * 5120;
    const int kofs = 4096 + kvg * 128, vofs = 4608 + kvg * 128;
    const int ntA = qa / 4 + 1, nt = qbig / 4 + 1;
    const int qposA = qa * 16 + lrow, qposB = qbig * 16 + lrow;
    const int rsw = lrow & 7;

    bf16x8 aqA[4], aqB[4];
#pragma unroll
    for (int kc = 0; kc < 4; ++kc) {
        bf16x8 ta = *reinterpret_cast<const bf16x8*>(
            &qkv[base + (size_t)(qa * 16 + lrow) * 5120 + h * 128 + kc * 32 + lkg * 8]);
        bf16x8 tb = *reinterpret_cast<const bf16x8*>(
            &qkv[base + (size_t)(qbig * 16 + lrow) * 5120 + h * 128 + kc * 32 + lkg * 8]);
#pragma unroll
        for (int i = 0; i < 8; ++i) {
            ta[i] = (__bf16)((float)ta[i] * 0.08838834764831845f);
            tb[i] = (__bf16)((float)tb[i] * 0.08838834764831845f);
        }
        aqA[kc] = ta; aqB[kc] = tb;
    }

    f32x4 accA[8] = {}, accB[8] = {};
    float mA = -1e30f, lA = 0.f, mB = -1e30f, lB = 0.f;
    __bf16* PwA = &Ps[wave][0][0];
    __bf16* PwB = &Ps[wave][1][0];

    auto stageK = [&](int t, int buf) {
        const int kv0 = (t < nt) ? t * 64 : 0;
#pragma unroll
        for (int c = 0; c < 2; ++c) {
            const int chunk = c * 8 + wave;
            const int row = chunk * 4 + (lane >> 4);
            const int gslot = (lane & 15) ^ (row & 7);
            gload16(&qkv[base + (size_t)(kv0 + row) * 5120 + kofs + gslot * 8],
                    &Ks[buf][chunk * 512]);
        }
    };
    auto loadV = [&](int t, uint4 (&vr)[2]) {
        const int kv0 = (t < nt) ? t * 64 : 0;
#pragma unroll
        for (int r = 0; r < 2; ++r)
            vr[r] = *reinterpret_cast<const uint4*>(
                &qkv[base + (size_t)(kv0 + lane) * 5120 + vofs + wave * 16 + r * 8]);
    };
    auto writeV = [&](uint4 (&vr)[2], int buf) {
#pragma unroll
        for (int r = 0; r < 2; ++r) {
            const __bf16* pv = reinterpret_cast<const __bf16*>(&vr[r]);
#pragma unroll
            for (int j = 0; j < 8; ++j) {
                const int d = wave * 16 + r * 8 + j;
                Vs[buf][d * 64 + (((lane >> 3) ^ j) << 3) + (lane & 7)] = pv[j];
            }
        }
    };

    auto smax = [&](f32x4 (&st)[4], float& m_i, float& l_i, f32x4 (&acc)[8],
                    int qpos, int kv0, bool maskit, __bf16* Pw) {
        float sv[16]; float pmax = -1e30f;
#pragma unroll
        for (int f = 0; f < 4; ++f)
#pragma unroll
            for (int j = 0; j < 4; ++j) {
                float x = st[f][j];
                if (maskit) {
                    const int kvpos = kv0 + f * 16 + lkg * 4 + j;
                    if (kvpos > qpos) x = -1e30f;
                }
                sv[f * 4 + j] = x;
                pmax = fmaxf(pmax, x);
            }
        pmax = fmaxf(pmax, __shfl_xor(pmax, 16));
        pmax = fmaxf(pmax, __shfl_xor(pmax, 32));
        if (!__all(pmax - m_i <= 8.f)) {
            const float m_new = fmaxf(m_i, pmax);
            const float sf = __expf(m_i - m_new);
            m_i = m_new;
            l_i *= sf;
            float sfj[4];
#pragma unroll
            for (int j = 0; j < 4; ++j) sfj[j] = __shfl(sf, lkg * 4 + j);
#pragma unroll
            for (int f = 0; f < 8; ++f)
#pragma unroll
                for (int j = 0; j < 4; ++j) acc[f][j] *= sfj[j];
        }
        float ladd = 0.f;
#pragma unroll
        for (int f = 0; f < 4; ++f) {
            bf16x4 pb;
#pragma unroll
            for (int j = 0; j < 4; ++j) {
                const float p = __expf(sv[f * 4 + j] - m_i);
                ladd += p;
                pb[j] = (__bf16)p;
            }
            const int slot = (f * 2 + (lkg >> 1)) ^ rsw;
            *reinterpret_cast<bf16x4*>(&Pw[lrow * 64 + slot * 8 + (lkg & 1) * 4]) = pb;
        }
        ladd += __shfl_xor(ladd, 16);
        ladd += __shfl_xor(ladd, 32);
        l_i += ladd;
    };

    auto body = [&](int t, uint4 (&vcur)[2], uint4 (&vnext)[2]) {
        const int kbuf = t & 1;
        __builtin_amdgcn_s_barrier();
        asm volatile("" ::: "memory");
        loadV(t + 1, vnext);
        stageK(t + 1, kbuf ^ 1);
        asm volatile("s_waitcnt vmcnt(4)" ::: "memory");
        writeV(vcur, kbuf);
        asm volatile("s_waitcnt lgkmcnt(0)" ::: "memory");
        __builtin_amdgcn_s_barrier();
        asm volatile("" ::: "memory");

        const bool doA = t < ntA;
        f32x4 stA[4] = {}, stB[4] = {};
#pragma unroll
        for (int kc = 0; kc < 4; ++kc)
#pragma unroll
            for (int f = 0; f < 4; ++f) {
                bf16x8 ak = *reinterpret_cast<const bf16x8*>(
                    &Ks[kbuf][(f * 16 + lrow) * 128 + (((kc * 4 + lkg) ^ rsw) << 3)]);
                stB[f] = __builtin_amdgcn_mfma_f32_16x16x32_bf16(ak, aqB[kc], stB[f], 0, 0, 0);
                if (doA)
                    stA[f] = __builtin_amdgcn_mfma_f32_16x16x32_bf16(ak, aqA[kc], stA[f], 0, 0, 0);
            }
        if (doA) smax(stA, mA, lA, accA, qposA, t * 64, t == ntA - 1, PwA);
        smax(stB, mB, lB, accB, qposB, t * 64, t == nt - 1, PwB);
#pragma unroll
        for (int kk = 0; kk < 2; ++kk) {
            const int pslot = ((kk * 4 + lkg) ^ rsw) << 3;
            bf16x8 apB = *reinterpret_cast<const bf16x8*>(&PwB[lrow * 64 + pslot]);
            bf16x8 apA;
            if (doA) apA = *reinterpret_cast<const bf16x8*>(&PwA[lrow * 64 + pslot]);
#pragma unroll
            for (int f = 0; f < 8; ++f) {
                bf16x8 bv = *reinterpret_cast<const bf16x8*>(
                    &Vs[kbuf][(f * 16 + lrow) * 64 + pslot]);
                accB[f] = __builtin_amdgcn_mfma_f32_16x16x32_bf16(apB, bv, accB[f], 0, 0, 0);
                if (doA)
                    accA[f] = __builtin_amdgcn_mfma_f32_16x16x32_bf16(apA, bv, accA[f], 0, 0, 0);
            }
        }
    };

    uint4 vrA[2], vrB[2];
    loadV(0, vrA);
    stageK(0, 0);
    for (int t = 0; t < nt; t += 2) {
        body(t, vrA, vrB);
        if (t + 1 < nt) body(t + 1, vrB, vrA);
    }
    asm volatile("s_waitcnt vmcnt(0)" ::: "memory");

    float linvA[4], linvB[4];
#pragma unroll
    for (int j = 0; j < 4; ++j) {
        linvA[j] = 1.0f / __shfl(lA, lkg * 4 + j);
        linvB[j] = 1.0f / __shfl(lB, lkg * 4 + j);
    }
#pragma unroll
    for (int f = 0; f < 8; ++f)
#pragma unroll
        for (int j = 0; j < 4; ++j) {
            out[((size_t)b * 1024 + qa * 16 + lkg * 4 + j) * 4096 + h * 128 + f * 16 + lrow] =
                (__bf16)(accA[f][j] * linvA[j]);
            out[((size_t)b * 1024 + qbig * 16 + lkg * 4 + j) * 4096 + h * 128 + f * 16 + lrow] =
                (__bf16)(accB[f][j] * linvB[j]);
        }
}

// ---------------------------------------------------------------------------
extern "C" void kernel_launch(void* const* d_in, const int* in_sizes, int n_in,
                              void* d_out, int out_size, void* d_ws, size_t ws_size,
                              hipStream_t stream) {
    const float* hidden = (const float*)d_in[0];
    const float* wq = (const float*)d_in[1];
    const float* wk = (const float*)d_in[2];
    const float* wv = (const float*)d_in[3];
    const float* wo = (const float*)d_in[4];
    const float* qnw = (const float*)d_in[5];
    const float* knw = (const float*)d_in[6];
    const float* cosT = (const float*)d_in[7];
    const float* sinT = (const float*)d_in[8];
    const int* ptab = (const int*)d_in[9];

    float* outp = (float*)d_out;                 // (2,1024,2048)
    float* cacheK = outp + 4194304;              // (128,4,32,128)
    float* cacheV = cacheK + 2097152;

    char* ws = (char*)d_ws;
    __bf16* hbf    = (__bf16*)ws;                       // 2048x2048
    __bf16* w1bf   = (__bf16*)(ws + 8388608);           // 5120x2048 (wq|wk|wv)
    __bf16* wobf   = (__bf16*)(ws + 29360128);          // 2048x4096
    __bf16* qkvbf  = (__bf16*)(ws + 46137344);          // 2048x5120
    __bf16* attnbf = (__bf16*)ws;                       // 2048x4096 (overlay: hbf/w1bf dead)
    float*  opart  = (float*)(ws + 46137344);           // 2048x2048 f32 (overlay: qkvbf dead)

    cvt5<<<22528, 256, 0, stream>>>(hidden, wq, wk, wv, wo,
                                    hbf, w1bf, w1bf + (size_t)4096 * 2048,
                                    w1bf + (size_t)4608 * 2048, wobf);

    // QKV projection: (2048x2048) @ (5120x2048)^T -> qkvbf bf16; 256 blocks (16x16)
    gemm8p<5, 1><<<256, 512, 0, stream>>>(hbf, w1bf, qkvbf, nullptr,
                                          2048, 5120, 2048, 256, 16, 2048);

    hipMemsetAsync(cacheK, 0, (size_t)4194304 * 4, stream);
    norm_rope_cache<<<2048, 256, 0, stream>>>(qkvbf, cosT, sinT, qnw, knw, ptab, cacheK, cacheV);

    attn_fwd<<<dim3(32, 4, 2), 512, 0, stream>>>(qkvbf, attnbf);

    // out projection: (2048x4096) @ (2048x4096)^T -> f32, splitK2; 256 blocks (128 tiles x 2)
    gemm8p<4, 0><<<256, 512, 0, stream>>>(attnbf, wobf, outp, opart,
                                          2048, 2048, 4096, 128, 8, 2048);
    reduce_add<<<2048, 256, 0, stream>>>(outp, opart, 4194304 / 4);
}